// Round 5
// baseline (752.557 us; speedup 1.0000x reference)
//
#include <hip/hip_runtime.h>
#include <hip/hip_bf16.h>

#define N_NODES 100000
#define N_EDGES 1600000
#define NFEAT   128
#define NGRAPH  256
#define NACT    32
#define ECAP    64
#define OVF_CAP 8192

#define BIN_SHIFT 7
#define BIN_NODES 128                                   // 1 << BIN_SHIFT
#define NBINS ((N_NODES + BIN_NODES - 1) / BIN_NODES)   // 782
#define BIN_CAP 2560                                    // ~11 sigma over E=2048

typedef __attribute__((ext_vector_type(8))) short bf16x8;
typedef __attribute__((ext_vector_type(4))) float f32x4;

__device__ inline unsigned short f2bf(float f) {
  __hip_bfloat16 b = __float2bfloat16(f);
  return *reinterpret_cast<unsigned short*>(&b);
}

// ---------------- dinv from counts (cnt == dst-degree) ----------------
__global__ __launch_bounds__(256) void dinv_kernel(const int* __restrict__ cnt,
                                                   float* __restrict__ dinv) {
  int n = blockIdx.x * 256 + threadIdx.x;
  if (n < N_NODES) dinv[n] = rsqrtf((float)cnt[n] + 1.0f);
}

// ---------------- pass A: bin edges by dst>>7 (dense append writes) ----------
__global__ __launch_bounds__(256) void binscatter_kernel(const int* __restrict__ src,
                                                         const int* __restrict__ dst,
                                                         int* __restrict__ bin_cnt,
                                                         int2* __restrict__ bin_buf,
                                                         int* __restrict__ cnt,
                                                         int* __restrict__ ovf_cnt,
                                                         int* __restrict__ ovf) {
  int e = blockIdx.x * 256 + threadIdx.x;
  if (e >= N_EDGES) return;
  int s = src[e], d = dst[e];
  int b = d >> BIN_SHIFT;
  int pos = atomicAdd(&bin_cnt[b], 1);
  if (pos < BIN_CAP) {
    bin_buf[(size_t)b * BIN_CAP + pos] = make_int2(s, d);
  } else {                       // ~never: count the edge, defer to ovf fixup
    atomicAdd(&cnt[d], 1);
    int o = atomicAdd(ovf_cnt, 1);
    if (o < OVF_CAP) { ovf[2 * o] = s; ovf[2 * o + 1] = d; }
  }
}

// ---------------- pass B: per-bin elist build in LDS, coalesced writeback ------
__global__ __launch_bounds__(256) void binexpand_kernel(const int2* __restrict__ bin_buf,
                                                        const int* __restrict__ bin_cnt,
                                                        int* __restrict__ cnt,
                                                        int* __restrict__ elist,
                                                        int* __restrict__ ovf_cnt,
                                                        int* __restrict__ ovf) {
  __shared__ int lcnt[BIN_NODES];
  __shared__ int lel[BIN_NODES * ECAP];     // 32 KB
  int b = blockIdx.x, tid = threadIdx.x;
  int n0 = b << BIN_SHIFT;
  if (tid < BIN_NODES) lcnt[tid] = 0;
  __syncthreads();
  int m = bin_cnt[b]; if (m > BIN_CAP) m = BIN_CAP;
  for (int e = tid; e < m; e += 256) {
    int2 p = bin_buf[(size_t)b * BIN_CAP + e];   // coalesced 8B
    int ln = p.y - n0;
    int pos = atomicAdd(&lcnt[ln], 1);
    if (pos < ECAP) {
      lel[(ln << 6) + pos] = p.x;
    } else {                                  // high-degree node: ovf fixup
      int o = atomicAdd(ovf_cnt, 1);
      if (o < OVF_CAP) { ovf[2 * o] = p.x; ovf[2 * o + 1] = p.y; }
    }
  }
  __syncthreads();
  if (tid < BIN_NODES) {
    int n = n0 + tid;
    if (n < N_NODES) cnt[n] += lcnt[tid];   // no race: bin owns node range,
  }                                         // pass A fully retired (stream order)
  int4* gel = (int4*)(elist + (size_t)n0 * ECAP);     // elist alloc is padded
  const int4* lel4 = (const int4*)lel;
  for (int i = tid; i < BIN_NODES * ECAP / 4; i += 256) gel[i] = lel4[i];
}

// ---------------- Wt[n][k] = bf16(W[k][n]) — once per call ----------
__global__ __launch_bounds__(256) void wt_kernel(const float* __restrict__ W,
                                                 unsigned short* __restrict__ Wt) {
  int i = blockIdx.x * 256 + threadIdx.x;
  if (i >= NFEAT * NFEAT) return;
  int n = i >> 7, k = i & 127;
  Wt[n * NFEAT + k] = f2bf(W[k * NFEAT + n]);
}

// ---------------- C[N,128](bf16) = (relu?)A[N,128](f32) @ W via MFMA ------------
__global__ __launch_bounds__(256) void gemm_mfma_kernel(const float* __restrict__ A,
                                                        const unsigned short* __restrict__ Wt,
                                                        unsigned short* __restrict__ C,
                                                        int relu_in) {
  int tid = threadIdx.x;
  int wave = tid >> 6, lane = tid & 63;
  int q = lane >> 4, r = lane & 15;
  int m0 = blockIdx.x * 64 + wave * 16;
  int arow = m0 + r; if (arow > N_NODES - 1) arow = N_NODES - 1;
  const float* Arow = A + (size_t)arow * NFEAT;

  f32x4 acc[8];
  #pragma unroll
  for (int t = 0; t < 8; ++t) acc[t] = (f32x4){0.f, 0.f, 0.f, 0.f};

  #pragma unroll
  for (int s = 0; s < 4; ++s) {
    int k0 = s * 32 + q * 8;
    float4 a0 = *(const float4*)(Arow + k0);
    float4 a1 = *(const float4*)(Arow + k0 + 4);
    if (relu_in) {
      a0.x = fmaxf(a0.x, 0.f); a0.y = fmaxf(a0.y, 0.f);
      a0.z = fmaxf(a0.z, 0.f); a0.w = fmaxf(a0.w, 0.f);
      a1.x = fmaxf(a1.x, 0.f); a1.y = fmaxf(a1.y, 0.f);
      a1.z = fmaxf(a1.z, 0.f); a1.w = fmaxf(a1.w, 0.f);
    }
    bf16x8 af;
    af[0] = (short)f2bf(a0.x); af[1] = (short)f2bf(a0.y);
    af[2] = (short)f2bf(a0.z); af[3] = (short)f2bf(a0.w);
    af[4] = (short)f2bf(a1.x); af[5] = (short)f2bf(a1.y);
    af[6] = (short)f2bf(a1.z); af[7] = (short)f2bf(a1.w);
    #pragma unroll
    for (int t = 0; t < 8; ++t) {
      bf16x8 bf = *(const bf16x8*)(Wt + (size_t)(t * 16 + r) * NFEAT + k0);
      acc[t] = __builtin_amdgcn_mfma_f32_16x16x32_bf16(af, bf, acc[t], 0, 0, 0);
    }
  }

  #pragma unroll
  for (int t = 0; t < 8; ++t) {
    #pragma unroll
    for (int rr = 0; rr < 4; ++rr) {
      int row = m0 + q * 4 + rr;
      if (row < N_NODES)
        C[(size_t)row * NFEAT + t * 16 + r] = f2bf(acc[t][rr]);
    }
  }
}

// ---------------- gather aggregation: one wave per dst node, 8 gathers in flight
__global__ __launch_bounds__(256) void agg_kernel(const __hip_bfloat162* __restrict__ h2,
                                                  const int* __restrict__ elist,
                                                  const int* __restrict__ cnt,
                                                  const float* __restrict__ dinv,
                                                  const float* __restrict__ bias,
                                                  float* __restrict__ out) {
  int n = (blockIdx.x * 256 + threadIdx.x) >> 6;
  int lane = threadIdx.x & 63;
  if (n >= N_NODES) return;
  float dn = dinv[n];
  int c = cnt[n]; c = (c > ECAP) ? ECAP : c;
  const int* el = elist + (size_t)n * ECAP;

  int   s_l = (lane < c) ? el[lane] : 0;
  float w_l = (lane < c) ? dinv[s_l] * dn : 0.f;

  float2 hv = __bfloat1622float2(h2[(size_t)n * 64 + lane]);
  float sw = dn * dn;
  float ax = sw * hv.x, ay = sw * hv.y;

  int j = 0;
  for (; j + 8 <= c; j += 8) {
    int   s0 = __shfl(s_l, j),     s1 = __shfl(s_l, j + 1);
    int   s2 = __shfl(s_l, j + 2), s3 = __shfl(s_l, j + 3);
    int   s4 = __shfl(s_l, j + 4), s5 = __shfl(s_l, j + 5);
    int   s6 = __shfl(s_l, j + 6), s7 = __shfl(s_l, j + 7);
    float w0 = __shfl(w_l, j),     w1 = __shfl(w_l, j + 1);
    float w2 = __shfl(w_l, j + 2), w3 = __shfl(w_l, j + 3);
    float w4 = __shfl(w_l, j + 4), w5 = __shfl(w_l, j + 5);
    float w6 = __shfl(w_l, j + 6), w7 = __shfl(w_l, j + 7);
    float2 v0 = __bfloat1622float2(h2[(size_t)s0 * 64 + lane]);
    float2 v1 = __bfloat1622float2(h2[(size_t)s1 * 64 + lane]);
    float2 v2 = __bfloat1622float2(h2[(size_t)s2 * 64 + lane]);
    float2 v3 = __bfloat1622float2(h2[(size_t)s3 * 64 + lane]);
    float2 v4 = __bfloat1622float2(h2[(size_t)s4 * 64 + lane]);
    float2 v5 = __bfloat1622float2(h2[(size_t)s5 * 64 + lane]);
    float2 v6 = __bfloat1622float2(h2[(size_t)s6 * 64 + lane]);
    float2 v7 = __bfloat1622float2(h2[(size_t)s7 * 64 + lane]);
    ax = fmaf(w0, v0.x, ax); ay = fmaf(w0, v0.y, ay);
    ax = fmaf(w1, v1.x, ax); ay = fmaf(w1, v1.y, ay);
    ax = fmaf(w2, v2.x, ax); ay = fmaf(w2, v2.y, ay);
    ax = fmaf(w3, v3.x, ax); ay = fmaf(w3, v3.y, ay);
    ax = fmaf(w4, v4.x, ax); ay = fmaf(w4, v4.y, ay);
    ax = fmaf(w5, v5.x, ax); ay = fmaf(w5, v5.y, ay);
    ax = fmaf(w6, v6.x, ax); ay = fmaf(w6, v6.y, ay);
    ax = fmaf(w7, v7.x, ax); ay = fmaf(w7, v7.y, ay);
  }
  if (j + 4 <= c) {
    int   s0 = __shfl(s_l, j),     s1 = __shfl(s_l, j + 1);
    int   s2 = __shfl(s_l, j + 2), s3 = __shfl(s_l, j + 3);
    float w0 = __shfl(w_l, j),     w1 = __shfl(w_l, j + 1);
    float w2 = __shfl(w_l, j + 2), w3 = __shfl(w_l, j + 3);
    float2 v0 = __bfloat1622float2(h2[(size_t)s0 * 64 + lane]);
    float2 v1 = __bfloat1622float2(h2[(size_t)s1 * 64 + lane]);
    float2 v2 = __bfloat1622float2(h2[(size_t)s2 * 64 + lane]);
    float2 v3 = __bfloat1622float2(h2[(size_t)s3 * 64 + lane]);
    ax = fmaf(w0, v0.x, ax); ay = fmaf(w0, v0.y, ay);
    ax = fmaf(w1, v1.x, ax); ay = fmaf(w1, v1.y, ay);
    ax = fmaf(w2, v2.x, ax); ay = fmaf(w2, v2.y, ay);
    ax = fmaf(w3, v3.x, ax); ay = fmaf(w3, v3.y, ay);
    j += 4;
  }
  for (; j < c; ++j) {
    int   s = __shfl(s_l, j);
    float w = __shfl(w_l, j);
    float2 v = __bfloat1622float2(h2[(size_t)s * 64 + lane]);
    ax = fmaf(w, v.x, ax); ay = fmaf(w, v.y, ay);
  }
  float2 b = ((const float2*)bias)[lane];
  float2 r; r.x = ax + b.x; r.y = ay + b.y;
  ((float2*)out)[(size_t)n * 64 + lane] = r;
}

// ---------------- overflow edges (expected count: 0) ----------------
__global__ __launch_bounds__(128) void ovf_kernel(const __hip_bfloat16* __restrict__ h,
                                                  const int* __restrict__ ovf,
                                                  const int* __restrict__ ovf_cnt,
                                                  const float* __restrict__ dinv,
                                                  float* __restrict__ out) {
  int m = *ovf_cnt; if (m > OVF_CAP) m = OVF_CAP;
  for (int p = blockIdx.x; p < m; p += gridDim.x) {
    int s = ovf[2 * p], d = ovf[2 * p + 1];
    float w = dinv[s] * dinv[d];
    for (int f = threadIdx.x; f < NFEAT; f += blockDim.x)
      atomicAdd(&out[(size_t)d * NFEAT + f],
                w * __bfloat162float(h[(size_t)s * NFEAT + f]));
  }
}

// ---------------- per-graph node counts via binary search (batch sorted) --------
__global__ __launch_bounds__(256) void gcnt_kernel(const int* __restrict__ batch,
                                                   float* __restrict__ invcnt) {
  int g = blockIdx.x * 256 + threadIdx.x;
  if (g >= NGRAPH) return;
  int lo = 0, hi = N_NODES;
  while (lo < hi) { int mid = (lo + hi) >> 1; if (batch[mid] < g) lo = mid + 1; else hi = mid; }
  int lo2 = lo, hi2 = N_NODES;
  while (lo2 < hi2) { int mid = (lo2 + hi2) >> 1; if (batch[mid] < g + 1) lo2 = mid + 1; else hi2 = mid; }
  int c = lo2 - lo;
  invcnt[g] = 1.0f / fmaxf((float)c, 1.0f);
}

// ---------------- pooled sum of relu(h) by (sorted) batch ----------------
#define PCHUNK 64
__global__ __launch_bounds__(64) void pool_kernel(const float* __restrict__ h,
                                                  const int* __restrict__ batch,
                                                  float* __restrict__ gsum) {
  int lane = threadIdx.x;
  int n0 = blockIdx.x * PCHUNK;
  if (n0 >= N_NODES) return;
  int n1 = n0 + PCHUNK; if (n1 > N_NODES) n1 = N_NODES;
  const float2* h2 = (const float2*)h;
  float ax = 0.f, ay = 0.f;
  int cur = batch[n0];
  for (int n = n0; n < n1; ++n) {
    int b = batch[n];                 // wave-uniform
    if (b != cur) {
      atomicAdd(&gsum[cur * NFEAT + 2 * lane], ax);
      atomicAdd(&gsum[cur * NFEAT + 2 * lane + 1], ay);
      ax = 0.f; ay = 0.f; cur = b;
    }
    float2 v = h2[(size_t)n * 64 + lane];
    ax += fmaxf(v.x, 0.f);
    ay += fmaxf(v.y, 0.f);
  }
  atomicAdd(&gsum[cur * NFEAT + 2 * lane], ax);
  atomicAdd(&gsum[cur * NFEAT + 2 * lane + 1], ay);
}

// ---------------- MLP head ----------------
__global__ __launch_bounds__(128) void mlp_kernel(const float* __restrict__ gsum,
                                                  const float* __restrict__ invcnt,
                                                  const float* __restrict__ Wl1,
                                                  const float* __restrict__ bl1,
                                                  const float* __restrict__ Wl2,
                                                  const float* __restrict__ bl2,
                                                  float* __restrict__ out) {
  __shared__ float gr[NFEAT];
  __shared__ float t1[NFEAT];
  int g = blockIdx.x, t = threadIdx.x;
  gr[t] = gsum[g * NFEAT + t] * invcnt[g];
  __syncthreads();
  float acc = bl1[t];
  for (int k = 0; k < NFEAT; ++k) acc = fmaf(gr[k], Wl1[k * NFEAT + t], acc);
  t1[t] = fmaxf(acc, 0.f);
  __syncthreads();
  if (t < NACT) {
    float a2 = bl2[t];
    for (int k = 0; k < NFEAT; ++k) a2 = fmaf(t1[k], Wl2[k * NACT + t], a2);
    out[g * NACT + t] = a2;
  }
}

extern "C" void kernel_launch(void* const* d_in, const int* in_sizes, int n_in,
                              void* d_out, int out_size, void* d_ws, size_t ws_size,
                              hipStream_t stream) {
  const float* x    = (const float*)d_in[0];
  const int*   ei   = (const int*)d_in[1];
  const int*   batch= (const int*)d_in[2];
  const float* W1   = (const float*)d_in[3];
  const float* b1   = (const float*)d_in[4];
  const float* W2   = (const float*)d_in[5];
  const float* b2   = (const float*)d_in[6];
  const float* Wl1  = (const float*)d_in[7];
  const float* bl1  = (const float*)d_in[8];
  const float* Wl2  = (const float*)d_in[9];
  const float* bl2  = (const float*)d_in[10];
  float* out = (float*)d_out;

  const int* srcp = ei;            // edge_index[0]
  const int* dstp = ei + N_EDGES;  // edge_index[1]

  // workspace bump allocator (512B aligned); zeroed region first.
  char* base = (char*)d_ws;
  size_t off = 0;
  auto alloc = [&](size_t bytes) -> void* {
    void* p = base + off;
    off += (bytes + 511) & ~(size_t)511;
    return p;
  };
  int*   cnt     = (int*)alloc((size_t)N_NODES * 4);
  int*   ovfc    = (int*)alloc(4);
  float* gsum    = (float*)alloc((size_t)NGRAPH * NFEAT * 4);
  int*   bin_cnt = (int*)alloc((size_t)NBINS * 4);
  size_t zspan   = off;  // everything above must start zeroed
  float* dinv    = (float*)alloc((size_t)N_NODES * 4);
  float* invcnt  = (float*)alloc((size_t)NGRAPH * 4);
  int*   elist   = (int*)alloc((size_t)NBINS * BIN_NODES * ECAP * 4); // padded
  int*   ovf     = (int*)alloc((size_t)OVF_CAP * 2 * 4);
  int2*  bin_buf = (int2*)alloc((size_t)NBINS * BIN_CAP * 8);
  unsigned short* Wt1 = (unsigned short*)alloc((size_t)NFEAT * NFEAT * 2);
  unsigned short* Wt2 = (unsigned short*)alloc((size_t)NFEAT * NFEAT * 2);
  unsigned short* A = (unsigned short*)alloc((size_t)N_NODES * NFEAT * 2); // bf16 h
  float* B       = (float*)alloc((size_t)N_NODES * NFEAT * 4);             // agg out

  hipMemsetAsync(d_ws, 0, zspan, stream);

  const int EB = (N_EDGES + 255) / 256;   // 6250
  const int NB = (N_NODES + 255) / 256;   // 391
  const int GB = (N_NODES + 63) / 64;     // 1563 gemm blocks

  binscatter_kernel<<<EB, 256, 0, stream>>>(srcp, dstp, bin_cnt, bin_buf, cnt, ovfc, ovf);
  binexpand_kernel<<<NBINS, 256, 0, stream>>>(bin_buf, bin_cnt, cnt, elist, ovfc, ovf);
  dinv_kernel<<<NB, 256, 0, stream>>>(cnt, dinv);
  wt_kernel<<<NFEAT * NFEAT / 256, 256, 0, stream>>>(W1, Wt1);
  wt_kernel<<<NFEAT * NFEAT / 256, 256, 0, stream>>>(W2, Wt2);

  // layer 1: A(bf16) = x @ W1 ; B = agg(A) + selfloop + b1 (relu deferred to gemm2)
  gemm_mfma_kernel<<<GB, 256, 0, stream>>>(x, Wt1, A, 0);
  agg_kernel<<<N_NODES / 4, 256, 0, stream>>>((const __hip_bfloat162*)A, elist, cnt, dinv, b1, B);
  ovf_kernel<<<64, 128, 0, stream>>>((const __hip_bfloat16*)A, ovf, ovfc, dinv, B);

  // layer 2: A(bf16) = relu(B) @ W2 ; B = agg(A) + selfloop + b2 (relu at pool)
  gemm_mfma_kernel<<<GB, 256, 0, stream>>>(B, Wt2, A, 1);
  agg_kernel<<<N_NODES / 4, 256, 0, stream>>>((const __hip_bfloat162*)A, elist, cnt, dinv, b2, B);
  ovf_kernel<<<64, 128, 0, stream>>>((const __hip_bfloat16*)A, ovf, ovfc, dinv, B);

  // pool + head
  gcnt_kernel<<<1, 256, 0, stream>>>(batch, invcnt);
  pool_kernel<<<(N_NODES + PCHUNK - 1) / PCHUNK, 64, 0, stream>>>(B, batch, gsum);
  mlp_kernel<<<NGRAPH, 128, 0, stream>>>(gsum, invcnt, Wl1, bl1, Wl2, bl2, out);
}

// Round 6
// 416.831 us; speedup vs baseline: 1.8054x; 1.8054x over previous
//
#include <hip/hip_runtime.h>
#include <hip/hip_bf16.h>

#define N_NODES 100000
#define N_EDGES 1600000
#define NFEAT   128
#define NGRAPH  256
#define NACT    32
#define ECAP    64
#define OVF_CAP 8192

// ---- two-pass edge partition ----
#define BUCK_SHIFT 9
#define BUCK_NODES 512
#define NBUCK ((N_NODES + BUCK_NODES - 1) / BUCK_NODES)   // 196
#define SEGCAP 10240          // mean 8192, +22 sigma
#define CHUNK 4096            // edges per pass-1 block
#define NBLK1 ((N_EDGES + CHUNK - 1) / CHUNK)             // 391
#define BIN_NODES 128         // pass-2 nodes per block
#define NBLK2 ((N_NODES + BIN_NODES - 1) / BIN_NODES)     // 782

typedef __attribute__((ext_vector_type(8))) short bf16x8;
typedef __attribute__((ext_vector_type(4))) float f32x4;

__device__ inline unsigned short f2bf(float f) {
  __hip_bfloat16 b = __float2bfloat16(f);
  return *reinterpret_cast<unsigned short*>(&b);
}

// ---------------- dinv from counts (cnt == dst-degree) ----------------
__global__ __launch_bounds__(256) void dinv_kernel(const int* __restrict__ cnt,
                                                   float* __restrict__ dinv) {
  int n = blockIdx.x * 256 + threadIdx.x;
  if (n < N_NODES) dinv[n] = rsqrtf((float)cnt[n] + 1.0f);
}

// ---- pass 1: block-local bucket sort in LDS, dense segment flush ----
__global__ __launch_bounds__(256) void edgepart_kernel(const int* __restrict__ src,
                                                       const int* __restrict__ dst,
                                                       int* __restrict__ bucket_cursor,
                                                       int2* __restrict__ seg,
                                                       int* __restrict__ cnt,
                                                       int* __restrict__ ovf_cnt,
                                                       int* __restrict__ ovf) {
  __shared__ int2 stage[CHUNK];               // 32 KB
  __shared__ int hist[NBUCK], offs[NBUCK], cursor[NBUCK], gbase[NBUCK];
  __shared__ int sc[256];
  int tid = threadIdx.x;
  int e0 = blockIdx.x * CHUNK;
  int m = N_EDGES - e0; if (m > CHUNK) m = CHUNK;

  for (int i = tid; i < NBUCK; i += 256) hist[i] = 0;
  __syncthreads();

  // phase A: load edges into registers, count buckets
  int2 ed[CHUNK / 256];
  int nloc = 0;
  for (int i = tid; i < m; i += 256) {
    int2 p = make_int2(src[e0 + i], dst[e0 + i]);
    ed[nloc++] = p;
    atomicAdd(&hist[p.y >> BUCK_SHIFT], 1);
  }
  __syncthreads();

  // phase B: exclusive scan of hist (Hillis-Steele over 256 slots)
  sc[tid] = (tid < NBUCK) ? hist[tid] : 0;
  __syncthreads();
  for (int ofs = 1; ofs < 256; ofs <<= 1) {
    int t = (tid >= ofs) ? sc[tid - ofs] : 0;
    __syncthreads();
    sc[tid] += t;
    __syncthreads();
  }
  if (tid < NBUCK) {
    int o = tid ? sc[tid - 1] : 0;
    offs[tid] = o;
    cursor[tid] = o;
    gbase[tid] = hist[tid] ? atomicAdd(&bucket_cursor[tid], hist[tid]) : 0;
  }
  __syncthreads();

  // phase C: bucket-sort chunk into LDS staging
  for (int i = 0; i < nloc; ++i) {
    int2 p = ed[i];
    int pos = atomicAdd(&cursor[p.y >> BUCK_SHIFT], 1);
    stage[pos] = p;
  }
  __syncthreads();

  // phase D: flush runs to global segments (dense, mostly coalesced)
  for (int i = tid; i < m; i += 256) {
    int2 p = stage[i];
    int bd = p.y >> BUCK_SHIFT;
    int gpos = gbase[bd] + (i - offs[bd]);
    if (gpos < SEGCAP) {
      seg[(size_t)bd * SEGCAP + gpos] = p;
    } else {                                // ~never: count + defer to ovf fixup
      atomicAdd(&cnt[p.y], 1);
      int o = atomicAdd(ovf_cnt, 1);
      if (o < OVF_CAP) { ovf[2 * o] = p.x; ovf[2 * o + 1] = p.y; }
    }
  }
}

// ---- pass 2: per-128-node elist build in LDS, dense writeback ----
__global__ __launch_bounds__(256) void binbuild_kernel(const int2* __restrict__ seg,
                                                       const int* __restrict__ bucket_cursor,
                                                       int* __restrict__ cnt,
                                                       int* __restrict__ elist,
                                                       int* __restrict__ ovf_cnt,
                                                       int* __restrict__ ovf) {
  __shared__ int lcnt[BIN_NODES];
  __shared__ int lel[BIN_NODES * ECAP];     // 32 KB
  int tid = threadIdx.x;
  int n0 = blockIdx.x * BIN_NODES;
  int pb = n0 >> BUCK_SHIFT;
  if (tid < BIN_NODES) lcnt[tid] = 0;
  __syncthreads();
  int m = bucket_cursor[pb]; if (m > SEGCAP) m = SEGCAP;
  const int2* s = seg + (size_t)pb * SEGCAP;
  for (int e = tid; e < m; e += 256) {
    int2 p = s[e];                           // coalesced 8B, L2/LLC-hot
    unsigned ln = (unsigned)(p.y - n0);
    if (ln < (unsigned)BIN_NODES) {
      int pos = atomicAdd(&lcnt[ln], 1);
      if (pos < ECAP) {
        lel[(ln << 6) + pos] = p.x;
      } else {                               // high-degree node: ovf fixup
        int o = atomicAdd(ovf_cnt, 1);
        if (o < OVF_CAP) { ovf[2 * o] = p.x; ovf[2 * o + 1] = p.y; }
      }
    }
  }
  __syncthreads();
  if (tid < BIN_NODES) {
    int n = n0 + tid;
    if (n < N_NODES) cnt[n] += lcnt[tid];    // safe: block owns node range,
  }                                          // pass 1 fully retired (stream order)
  int4* gel = (int4*)(elist + (size_t)n0 * ECAP);   // elist alloc padded
  const int4* lel4 = (const int4*)lel;
  for (int i = tid; i < BIN_NODES * ECAP / 4; i += 256) gel[i] = lel4[i];
}

// ---------------- Wt[n][k] = bf16(W[k][n]) — once per call ----------
__global__ __launch_bounds__(256) void wt_kernel(const float* __restrict__ W,
                                                 unsigned short* __restrict__ Wt) {
  int i = blockIdx.x * 256 + threadIdx.x;
  if (i >= NFEAT * NFEAT) return;
  int n = i >> 7, k = i & 127;
  Wt[n * NFEAT + k] = f2bf(W[k * NFEAT + n]);
}

// ---------------- C[N,128](bf16) = (relu?)A[N,128](f32) @ W via MFMA ------------
__global__ __launch_bounds__(256) void gemm_mfma_kernel(const float* __restrict__ A,
                                                        const unsigned short* __restrict__ Wt,
                                                        unsigned short* __restrict__ C,
                                                        int relu_in) {
  int tid = threadIdx.x;
  int wave = tid >> 6, lane = tid & 63;
  int q = lane >> 4, r = lane & 15;
  int m0 = blockIdx.x * 64 + wave * 16;
  int arow = m0 + r; if (arow > N_NODES - 1) arow = N_NODES - 1;
  const float* Arow = A + (size_t)arow * NFEAT;

  f32x4 acc[8];
  #pragma unroll
  for (int t = 0; t < 8; ++t) acc[t] = (f32x4){0.f, 0.f, 0.f, 0.f};

  #pragma unroll
  for (int s = 0; s < 4; ++s) {
    int k0 = s * 32 + q * 8;
    float4 a0 = *(const float4*)(Arow + k0);
    float4 a1 = *(const float4*)(Arow + k0 + 4);
    if (relu_in) {
      a0.x = fmaxf(a0.x, 0.f); a0.y = fmaxf(a0.y, 0.f);
      a0.z = fmaxf(a0.z, 0.f); a0.w = fmaxf(a0.w, 0.f);
      a1.x = fmaxf(a1.x, 0.f); a1.y = fmaxf(a1.y, 0.f);
      a1.z = fmaxf(a1.z, 0.f); a1.w = fmaxf(a1.w, 0.f);
    }
    bf16x8 af;
    af[0] = (short)f2bf(a0.x); af[1] = (short)f2bf(a0.y);
    af[2] = (short)f2bf(a0.z); af[3] = (short)f2bf(a0.w);
    af[4] = (short)f2bf(a1.x); af[5] = (short)f2bf(a1.y);
    af[6] = (short)f2bf(a1.z); af[7] = (short)f2bf(a1.w);
    #pragma unroll
    for (int t = 0; t < 8; ++t) {
      bf16x8 bf = *(const bf16x8*)(Wt + (size_t)(t * 16 + r) * NFEAT + k0);
      acc[t] = __builtin_amdgcn_mfma_f32_16x16x32_bf16(af, bf, acc[t], 0, 0, 0);
    }
  }

  #pragma unroll
  for (int t = 0; t < 8; ++t) {
    #pragma unroll
    for (int rr = 0; rr < 4; ++rr) {
      int row = m0 + q * 4 + rr;
      if (row < N_NODES)
        C[(size_t)row * NFEAT + t * 16 + r] = f2bf(acc[t][rr]);
    }
  }
}

// ---------------- gather aggregation: one wave per dst node, 8 gathers in flight
__global__ __launch_bounds__(256) void agg_kernel(const __hip_bfloat162* __restrict__ h2,
                                                  const int* __restrict__ elist,
                                                  const int* __restrict__ cnt,
                                                  const float* __restrict__ dinv,
                                                  const float* __restrict__ bias,
                                                  float* __restrict__ out) {
  int n = (blockIdx.x * 256 + threadIdx.x) >> 6;
  int lane = threadIdx.x & 63;
  if (n >= N_NODES) return;
  float dn = dinv[n];
  int c = cnt[n]; c = (c > ECAP) ? ECAP : c;
  const int* el = elist + (size_t)n * ECAP;

  int   s_l = (lane < c) ? el[lane] : 0;
  float w_l = (lane < c) ? dinv[s_l] * dn : 0.f;

  float2 hv = __bfloat1622float2(h2[(size_t)n * 64 + lane]);
  float sw = dn * dn;
  float ax = sw * hv.x, ay = sw * hv.y;

  int j = 0;
  for (; j + 8 <= c; j += 8) {
    int   s0 = __shfl(s_l, j),     s1 = __shfl(s_l, j + 1);
    int   s2 = __shfl(s_l, j + 2), s3 = __shfl(s_l, j + 3);
    int   s4 = __shfl(s_l, j + 4), s5 = __shfl(s_l, j + 5);
    int   s6 = __shfl(s_l, j + 6), s7 = __shfl(s_l, j + 7);
    float w0 = __shfl(w_l, j),     w1 = __shfl(w_l, j + 1);
    float w2 = __shfl(w_l, j + 2), w3 = __shfl(w_l, j + 3);
    float w4 = __shfl(w_l, j + 4), w5 = __shfl(w_l, j + 5);
    float w6 = __shfl(w_l, j + 6), w7 = __shfl(w_l, j + 7);
    float2 v0 = __bfloat1622float2(h2[(size_t)s0 * 64 + lane]);
    float2 v1 = __bfloat1622float2(h2[(size_t)s1 * 64 + lane]);
    float2 v2 = __bfloat1622float2(h2[(size_t)s2 * 64 + lane]);
    float2 v3 = __bfloat1622float2(h2[(size_t)s3 * 64 + lane]);
    float2 v4 = __bfloat1622float2(h2[(size_t)s4 * 64 + lane]);
    float2 v5 = __bfloat1622float2(h2[(size_t)s5 * 64 + lane]);
    float2 v6 = __bfloat1622float2(h2[(size_t)s6 * 64 + lane]);
    float2 v7 = __bfloat1622float2(h2[(size_t)s7 * 64 + lane]);
    ax = fmaf(w0, v0.x, ax); ay = fmaf(w0, v0.y, ay);
    ax = fmaf(w1, v1.x, ax); ay = fmaf(w1, v1.y, ay);
    ax = fmaf(w2, v2.x, ax); ay = fmaf(w2, v2.y, ay);
    ax = fmaf(w3, v3.x, ax); ay = fmaf(w3, v3.y, ay);
    ax = fmaf(w4, v4.x, ax); ay = fmaf(w4, v4.y, ay);
    ax = fmaf(w5, v5.x, ax); ay = fmaf(w5, v5.y, ay);
    ax = fmaf(w6, v6.x, ax); ay = fmaf(w6, v6.y, ay);
    ax = fmaf(w7, v7.x, ax); ay = fmaf(w7, v7.y, ay);
  }
  if (j + 4 <= c) {
    int   s0 = __shfl(s_l, j),     s1 = __shfl(s_l, j + 1);
    int   s2 = __shfl(s_l, j + 2), s3 = __shfl(s_l, j + 3);
    float w0 = __shfl(w_l, j),     w1 = __shfl(w_l, j + 1);
    float w2 = __shfl(w_l, j + 2), w3 = __shfl(w_l, j + 3);
    float2 v0 = __bfloat1622float2(h2[(size_t)s0 * 64 + lane]);
    float2 v1 = __bfloat1622float2(h2[(size_t)s1 * 64 + lane]);
    float2 v2 = __bfloat1622float2(h2[(size_t)s2 * 64 + lane]);
    float2 v3 = __bfloat1622float2(h2[(size_t)s3 * 64 + lane]);
    ax = fmaf(w0, v0.x, ax); ay = fmaf(w0, v0.y, ay);
    ax = fmaf(w1, v1.x, ax); ay = fmaf(w1, v1.y, ay);
    ax = fmaf(w2, v2.x, ax); ay = fmaf(w2, v2.y, ay);
    ax = fmaf(w3, v3.x, ax); ay = fmaf(w3, v3.y, ay);
    j += 4;
  }
  for (; j < c; ++j) {
    int   s = __shfl(s_l, j);
    float w = __shfl(w_l, j);
    float2 v = __bfloat1622float2(h2[(size_t)s * 64 + lane]);
    ax = fmaf(w, v.x, ax); ay = fmaf(w, v.y, ay);
  }
  float2 b = ((const float2*)bias)[lane];
  float2 r; r.x = ax + b.x; r.y = ay + b.y;
  ((float2*)out)[(size_t)n * 64 + lane] = r;
}

// ---------------- overflow edges (expected count: 0) ----------------
__global__ __launch_bounds__(128) void ovf_kernel(const __hip_bfloat16* __restrict__ h,
                                                  const int* __restrict__ ovf,
                                                  const int* __restrict__ ovf_cnt,
                                                  const float* __restrict__ dinv,
                                                  float* __restrict__ out) {
  int m = *ovf_cnt; if (m > OVF_CAP) m = OVF_CAP;
  for (int p = blockIdx.x; p < m; p += gridDim.x) {
    int s = ovf[2 * p], d = ovf[2 * p + 1];
    float w = dinv[s] * dinv[d];
    for (int f = threadIdx.x; f < NFEAT; f += blockDim.x)
      atomicAdd(&out[(size_t)d * NFEAT + f],
                w * __bfloat162float(h[(size_t)s * NFEAT + f]));
  }
}

// ---------------- per-graph node counts via binary search (batch sorted) --------
__global__ __launch_bounds__(256) void gcnt_kernel(const int* __restrict__ batch,
                                                   float* __restrict__ invcnt) {
  int g = blockIdx.x * 256 + threadIdx.x;
  if (g >= NGRAPH) return;
  int lo = 0, hi = N_NODES;
  while (lo < hi) { int mid = (lo + hi) >> 1; if (batch[mid] < g) lo = mid + 1; else hi = mid; }
  int lo2 = lo, hi2 = N_NODES;
  while (lo2 < hi2) { int mid = (lo2 + hi2) >> 1; if (batch[mid] < g + 1) lo2 = mid + 1; else hi2 = mid; }
  int c = lo2 - lo;
  invcnt[g] = 1.0f / fmaxf((float)c, 1.0f);
}

// ---------------- pooled sum of relu(h) by (sorted) batch ----------------
#define PCHUNK 64
__global__ __launch_bounds__(64) void pool_kernel(const float* __restrict__ h,
                                                  const int* __restrict__ batch,
                                                  float* __restrict__ gsum) {
  int lane = threadIdx.x;
  int n0 = blockIdx.x * PCHUNK;
  if (n0 >= N_NODES) return;
  int n1 = n0 + PCHUNK; if (n1 > N_NODES) n1 = N_NODES;
  const float2* h2 = (const float2*)h;
  float ax = 0.f, ay = 0.f;
  int cur = batch[n0];
  for (int n = n0; n < n1; ++n) {
    int b = batch[n];                 // wave-uniform
    if (b != cur) {
      atomicAdd(&gsum[cur * NFEAT + 2 * lane], ax);
      atomicAdd(&gsum[cur * NFEAT + 2 * lane + 1], ay);
      ax = 0.f; ay = 0.f; cur = b;
    }
    float2 v = h2[(size_t)n * 64 + lane];
    ax += fmaxf(v.x, 0.f);
    ay += fmaxf(v.y, 0.f);
  }
  atomicAdd(&gsum[cur * NFEAT + 2 * lane], ax);
  atomicAdd(&gsum[cur * NFEAT + 2 * lane + 1], ay);
}

// ---------------- MLP head ----------------
__global__ __launch_bounds__(128) void mlp_kernel(const float* __restrict__ gsum,
                                                  const float* __restrict__ invcnt,
                                                  const float* __restrict__ Wl1,
                                                  const float* __restrict__ bl1,
                                                  const float* __restrict__ Wl2,
                                                  const float* __restrict__ bl2,
                                                  float* __restrict__ out) {
  __shared__ float gr[NFEAT];
  __shared__ float t1[NFEAT];
  int g = blockIdx.x, t = threadIdx.x;
  gr[t] = gsum[g * NFEAT + t] * invcnt[g];
  __syncthreads();
  float acc = bl1[t];
  for (int k = 0; k < NFEAT; ++k) acc = fmaf(gr[k], Wl1[k * NFEAT + t], acc);
  t1[t] = fmaxf(acc, 0.f);
  __syncthreads();
  if (t < NACT) {
    float a2 = bl2[t];
    for (int k = 0; k < NFEAT; ++k) a2 = fmaf(t1[k], Wl2[k * NACT + t], a2);
    out[g * NACT + t] = a2;
  }
}

extern "C" void kernel_launch(void* const* d_in, const int* in_sizes, int n_in,
                              void* d_out, int out_size, void* d_ws, size_t ws_size,
                              hipStream_t stream) {
  const float* x    = (const float*)d_in[0];
  const int*   ei   = (const int*)d_in[1];
  const int*   batch= (const int*)d_in[2];
  const float* W1   = (const float*)d_in[3];
  const float* b1   = (const float*)d_in[4];
  const float* W2   = (const float*)d_in[5];
  const float* b2   = (const float*)d_in[6];
  const float* Wl1  = (const float*)d_in[7];
  const float* bl1  = (const float*)d_in[8];
  const float* Wl2  = (const float*)d_in[9];
  const float* bl2  = (const float*)d_in[10];
  float* out = (float*)d_out;

  const int* srcp = ei;            // edge_index[0]
  const int* dstp = ei + N_EDGES;  // edge_index[1]

  // workspace bump allocator (512B aligned); zeroed region first.
  char* base = (char*)d_ws;
  size_t off = 0;
  auto alloc = [&](size_t bytes) -> void* {
    void* p = base + off;
    off += (bytes + 511) & ~(size_t)511;
    return p;
  };
  int*   cnt     = (int*)alloc((size_t)N_NODES * 4);
  int*   ovfc    = (int*)alloc(4);
  float* gsum    = (float*)alloc((size_t)NGRAPH * NFEAT * 4);
  int*   bucket_cursor = (int*)alloc((size_t)NBUCK * 4);
  size_t zspan   = off;  // everything above must start zeroed
  float* dinv    = (float*)alloc((size_t)N_NODES * 4);
  float* invcnt  = (float*)alloc((size_t)NGRAPH * 4);
  int*   elist   = (int*)alloc((size_t)NBLK2 * BIN_NODES * ECAP * 4); // padded
  int*   ovf     = (int*)alloc((size_t)OVF_CAP * 2 * 4);
  int2*  seg     = (int2*)alloc((size_t)NBUCK * SEGCAP * 8);          // 16 MB
  unsigned short* Wt1 = (unsigned short*)alloc((size_t)NFEAT * NFEAT * 2);
  unsigned short* Wt2 = (unsigned short*)alloc((size_t)NFEAT * NFEAT * 2);
  unsigned short* A = (unsigned short*)alloc((size_t)N_NODES * NFEAT * 2); // bf16 h
  float* B       = (float*)alloc((size_t)N_NODES * NFEAT * 4);             // agg out

  hipMemsetAsync(d_ws, 0, zspan, stream);

  const int NB = (N_NODES + 255) / 256;   // 391
  const int GB = (N_NODES + 63) / 64;     // 1563 gemm blocks

  edgepart_kernel<<<NBLK1, 256, 0, stream>>>(srcp, dstp, bucket_cursor, seg, cnt, ovfc, ovf);
  binbuild_kernel<<<NBLK2, 256, 0, stream>>>(seg, bucket_cursor, cnt, elist, ovfc, ovf);
  dinv_kernel<<<NB, 256, 0, stream>>>(cnt, dinv);
  wt_kernel<<<NFEAT * NFEAT / 256, 256, 0, stream>>>(W1, Wt1);
  wt_kernel<<<NFEAT * NFEAT / 256, 256, 0, stream>>>(W2, Wt2);

  // layer 1: A(bf16) = x @ W1 ; B = agg(A) + selfloop + b1 (relu deferred to gemm2)
  gemm_mfma_kernel<<<GB, 256, 0, stream>>>(x, Wt1, A, 0);
  agg_kernel<<<N_NODES / 4, 256, 0, stream>>>((const __hip_bfloat162*)A, elist, cnt, dinv, b1, B);
  ovf_kernel<<<64, 128, 0, stream>>>((const __hip_bfloat16*)A, ovf, ovfc, dinv, B);

  // layer 2: A(bf16) = relu(B) @ W2 ; B = agg(A) + selfloop + b2 (relu at pool)
  gemm_mfma_kernel<<<GB, 256, 0, stream>>>(B, Wt2, A, 1);
  agg_kernel<<<N_NODES / 4, 256, 0, stream>>>((const __hip_bfloat162*)A, elist, cnt, dinv, b2, B);
  ovf_kernel<<<64, 128, 0, stream>>>((const __hip_bfloat16*)A, ovf, ovfc, dinv, B);

  // pool + head
  gcnt_kernel<<<1, 256, 0, stream>>>(batch, invcnt);
  pool_kernel<<<(N_NODES + PCHUNK - 1) / PCHUNK, 64, 0, stream>>>(B, batch, gsum);
  mlp_kernel<<<NGRAPH, 128, 0, stream>>>(gsum, invcnt, Wl1, bl1, Wl2, bl2, out);
}

// Round 7
// 408.967 us; speedup vs baseline: 1.8401x; 1.0192x over previous
//
#include <hip/hip_runtime.h>
#include <hip/hip_bf16.h>

#define N_NODES 100000
#define N_EDGES 1600000
#define NFEAT   128
#define NGRAPH  256
#define NACT    32
#define ECAP    64
#define OVF_CAP 8192

// ---- two-pass edge partition ----
#define BUCK_SHIFT 9
#define BUCK_NODES 512
#define NBUCK ((N_NODES + BUCK_NODES - 1) / BUCK_NODES)   // 196
#define SEGCAP 10240          // mean 8192, +22 sigma
#define CHUNK 4096            // edges per pass-1 block
#define NBLK1 ((N_EDGES + CHUNK - 1) / CHUNK)             // 391
#define BIN_NODES 128         // pass-2 nodes per block
#define NBLK2 ((N_NODES + BIN_NODES - 1) / BIN_NODES)     // 782

typedef __attribute__((ext_vector_type(8))) short bf16x8;
typedef __attribute__((ext_vector_type(4))) float f32x4;

__device__ inline unsigned short f2bf(float f) {
  __hip_bfloat16 b = __float2bfloat16(f);
  return *reinterpret_cast<unsigned short*>(&b);
}

// ---------------- dinv from counts (cnt == dst-degree) ----------------
__global__ __launch_bounds__(256) void dinv_kernel(const int* __restrict__ cnt,
                                                   float* __restrict__ dinv) {
  int n = blockIdx.x * 256 + threadIdx.x;
  if (n < N_NODES) dinv[n] = rsqrtf((float)cnt[n] + 1.0f);
}

// ---- pass 1: block-local bucket sort in LDS, dense segment flush ----
// NOTE: no per-thread edge array (R6's version spilled it to scratch and
// serialized at 0.2% occupancy). Phase C re-reads edges from global (L2-hot).
__global__ __launch_bounds__(256) void edgepart_kernel(const int* __restrict__ src,
                                                       const int* __restrict__ dst,
                                                       int* __restrict__ bucket_cursor,
                                                       int2* __restrict__ seg,
                                                       int* __restrict__ cnt,
                                                       int* __restrict__ ovf_cnt,
                                                       int* __restrict__ ovf) {
  __shared__ int2 stage[CHUNK];               // 32 KB
  __shared__ int hist[NBUCK], offs[NBUCK], cursor[NBUCK], gbase[NBUCK];
  __shared__ int sc[256];
  int tid = threadIdx.x;
  int e0 = blockIdx.x * CHUNK;
  int m = N_EDGES - e0; if (m > CHUNK) m = CHUNK;

  for (int i = tid; i < NBUCK; i += 256) hist[i] = 0;
  __syncthreads();

  // phase A: histogram over dst buckets (dst read only)
  for (int i = tid; i < m; i += 256)
    atomicAdd(&hist[dst[e0 + i] >> BUCK_SHIFT], 1);
  __syncthreads();

  // phase B: exclusive scan of hist (Hillis-Steele over 256 slots)
  sc[tid] = (tid < NBUCK) ? hist[tid] : 0;
  __syncthreads();
  for (int ofs = 1; ofs < 256; ofs <<= 1) {
    int t = (tid >= ofs) ? sc[tid - ofs] : 0;
    __syncthreads();
    sc[tid] += t;
    __syncthreads();
  }
  if (tid < NBUCK) {
    int o = tid ? sc[tid - 1] : 0;
    offs[tid] = o;
    cursor[tid] = o;
    gbase[tid] = hist[tid] ? atomicAdd(&bucket_cursor[tid], hist[tid]) : 0;
  }
  __syncthreads();

  // phase C: re-read edges (coalesced, L2-hot), bucket-sort into LDS staging
  for (int i = tid; i < m; i += 256) {
    int2 p = make_int2(src[e0 + i], dst[e0 + i]);
    int pos = atomicAdd(&cursor[p.y >> BUCK_SHIFT], 1);
    stage[pos] = p;
  }
  __syncthreads();

  // phase D: flush runs to global segments (dense, mostly coalesced)
  for (int i = tid; i < m; i += 256) {
    int2 p = stage[i];
    int bd = p.y >> BUCK_SHIFT;
    int gpos = gbase[bd] + (i - offs[bd]);
    if (gpos < SEGCAP) {
      seg[(size_t)bd * SEGCAP + gpos] = p;
    } else {                                // ~never: count + defer to ovf fixup
      atomicAdd(&cnt[p.y], 1);
      int o = atomicAdd(ovf_cnt, 1);
      if (o < OVF_CAP) { ovf[2 * o] = p.x; ovf[2 * o + 1] = p.y; }
    }
  }
}

// ---- pass 2: per-128-node elist build in LDS, dense writeback ----
__global__ __launch_bounds__(256) void binbuild_kernel(const int2* __restrict__ seg,
                                                       const int* __restrict__ bucket_cursor,
                                                       int* __restrict__ cnt,
                                                       int* __restrict__ elist,
                                                       int* __restrict__ ovf_cnt,
                                                       int* __restrict__ ovf) {
  __shared__ int lcnt[BIN_NODES];
  __shared__ int lel[BIN_NODES * ECAP];     // 32 KB
  int tid = threadIdx.x;
  int n0 = blockIdx.x * BIN_NODES;
  int pb = n0 >> BUCK_SHIFT;
  if (tid < BIN_NODES) lcnt[tid] = 0;
  __syncthreads();
  int m = bucket_cursor[pb]; if (m > SEGCAP) m = SEGCAP;
  const int2* s = seg + (size_t)pb * SEGCAP;
  for (int e = tid; e < m; e += 256) {
    int2 p = s[e];                           // coalesced 8B, L2/LLC-hot
    unsigned ln = (unsigned)(p.y - n0);
    if (ln < (unsigned)BIN_NODES) {
      int pos = atomicAdd(&lcnt[ln], 1);
      if (pos < ECAP) {
        lel[(ln << 6) + pos] = p.x;
      } else {                               // high-degree node: ovf fixup
        int o = atomicAdd(ovf_cnt, 1);
        if (o < OVF_CAP) { ovf[2 * o] = p.x; ovf[2 * o + 1] = p.y; }
      }
    }
  }
  __syncthreads();
  if (tid < BIN_NODES) {
    int n = n0 + tid;
    if (n < N_NODES) cnt[n] += lcnt[tid];    // safe: block owns node range,
  }                                          // pass 1 fully retired (stream order)
  int4* gel = (int4*)(elist + (size_t)n0 * ECAP);   // elist alloc padded
  const int4* lel4 = (const int4*)lel;
  for (int i = tid; i < BIN_NODES * ECAP / 4; i += 256) gel[i] = lel4[i];
}

// ---------------- Wt[n][k] = bf16(W[k][n]) — once per call ----------
__global__ __launch_bounds__(256) void wt_kernel(const float* __restrict__ W,
                                                 unsigned short* __restrict__ Wt) {
  int i = blockIdx.x * 256 + threadIdx.x;
  if (i >= NFEAT * NFEAT) return;
  int n = i >> 7, k = i & 127;
  Wt[n * NFEAT + k] = f2bf(W[k * NFEAT + n]);
}

// ---------------- C[N,128](bf16) = (relu?)A[N,128](f32) @ W via MFMA ------------
__global__ __launch_bounds__(256) void gemm_mfma_kernel(const float* __restrict__ A,
                                                        const unsigned short* __restrict__ Wt,
                                                        unsigned short* __restrict__ C,
                                                        int relu_in) {
  int tid = threadIdx.x;
  int wave = tid >> 6, lane = tid & 63;
  int q = lane >> 4, r = lane & 15;
  int m0 = blockIdx.x * 64 + wave * 16;
  int arow = m0 + r; if (arow > N_NODES - 1) arow = N_NODES - 1;
  const float* Arow = A + (size_t)arow * NFEAT;

  f32x4 acc[8];
  #pragma unroll
  for (int t = 0; t < 8; ++t) acc[t] = (f32x4){0.f, 0.f, 0.f, 0.f};

  #pragma unroll
  for (int s = 0; s < 4; ++s) {
    int k0 = s * 32 + q * 8;
    float4 a0 = *(const float4*)(Arow + k0);
    float4 a1 = *(const float4*)(Arow + k0 + 4);
    if (relu_in) {
      a0.x = fmaxf(a0.x, 0.f); a0.y = fmaxf(a0.y, 0.f);
      a0.z = fmaxf(a0.z, 0.f); a0.w = fmaxf(a0.w, 0.f);
      a1.x = fmaxf(a1.x, 0.f); a1.y = fmaxf(a1.y, 0.f);
      a1.z = fmaxf(a1.z, 0.f); a1.w = fmaxf(a1.w, 0.f);
    }
    bf16x8 af;
    af[0] = (short)f2bf(a0.x); af[1] = (short)f2bf(a0.y);
    af[2] = (short)f2bf(a0.z); af[3] = (short)f2bf(a0.w);
    af[4] = (short)f2bf(a1.x); af[5] = (short)f2bf(a1.y);
    af[6] = (short)f2bf(a1.z); af[7] = (short)f2bf(a1.w);
    #pragma unroll
    for (int t = 0; t < 8; ++t) {
      bf16x8 bf = *(const bf16x8*)(Wt + (size_t)(t * 16 + r) * NFEAT + k0);
      acc[t] = __builtin_amdgcn_mfma_f32_16x16x32_bf16(af, bf, acc[t], 0, 0, 0);
    }
  }

  #pragma unroll
  for (int t = 0; t < 8; ++t) {
    #pragma unroll
    for (int rr = 0; rr < 4; ++rr) {
      int row = m0 + q * 4 + rr;
      if (row < N_NODES)
        C[(size_t)row * NFEAT + t * 16 + r] = f2bf(acc[t][rr]);
    }
  }
}

// ---------------- gather aggregation: one wave per dst node, 8 gathers in flight
__global__ __launch_bounds__(256) void agg_kernel(const __hip_bfloat162* __restrict__ h2,
                                                  const int* __restrict__ elist,
                                                  const int* __restrict__ cnt,
                                                  const float* __restrict__ dinv,
                                                  const float* __restrict__ bias,
                                                  float* __restrict__ out) {
  int n = (blockIdx.x * 256 + threadIdx.x) >> 6;
  int lane = threadIdx.x & 63;
  if (n >= N_NODES) return;
  float dn = dinv[n];
  int c = cnt[n]; c = (c > ECAP) ? ECAP : c;
  const int* el = elist + (size_t)n * ECAP;

  int   s_l = (lane < c) ? el[lane] : 0;
  float w_l = (lane < c) ? dinv[s_l] * dn : 0.f;

  float2 hv = __bfloat1622float2(h2[(size_t)n * 64 + lane]);
  float sw = dn * dn;
  float ax = sw * hv.x, ay = sw * hv.y;

  int j = 0;
  for (; j + 8 <= c; j += 8) {
    int   s0 = __shfl(s_l, j),     s1 = __shfl(s_l, j + 1);
    int   s2 = __shfl(s_l, j + 2), s3 = __shfl(s_l, j + 3);
    int   s4 = __shfl(s_l, j + 4), s5 = __shfl(s_l, j + 5);
    int   s6 = __shfl(s_l, j + 6), s7 = __shfl(s_l, j + 7);
    float w0 = __shfl(w_l, j),     w1 = __shfl(w_l, j + 1);
    float w2 = __shfl(w_l, j + 2), w3 = __shfl(w_l, j + 3);
    float w4 = __shfl(w_l, j + 4), w5 = __shfl(w_l, j + 5);
    float w6 = __shfl(w_l, j + 6), w7 = __shfl(w_l, j + 7);
    float2 v0 = __bfloat1622float2(h2[(size_t)s0 * 64 + lane]);
    float2 v1 = __bfloat1622float2(h2[(size_t)s1 * 64 + lane]);
    float2 v2 = __bfloat1622float2(h2[(size_t)s2 * 64 + lane]);
    float2 v3 = __bfloat1622float2(h2[(size_t)s3 * 64 + lane]);
    float2 v4 = __bfloat1622float2(h2[(size_t)s4 * 64 + lane]);
    float2 v5 = __bfloat1622float2(h2[(size_t)s5 * 64 + lane]);
    float2 v6 = __bfloat1622float2(h2[(size_t)s6 * 64 + lane]);
    float2 v7 = __bfloat1622float2(h2[(size_t)s7 * 64 + lane]);
    ax = fmaf(w0, v0.x, ax); ay = fmaf(w0, v0.y, ay);
    ax = fmaf(w1, v1.x, ax); ay = fmaf(w1, v1.y, ay);
    ax = fmaf(w2, v2.x, ax); ay = fmaf(w2, v2.y, ay);
    ax = fmaf(w3, v3.x, ax); ay = fmaf(w3, v3.y, ay);
    ax = fmaf(w4, v4.x, ax); ay = fmaf(w4, v4.y, ay);
    ax = fmaf(w5, v5.x, ax); ay = fmaf(w5, v5.y, ay);
    ax = fmaf(w6, v6.x, ax); ay = fmaf(w6, v6.y, ay);
    ax = fmaf(w7, v7.x, ax); ay = fmaf(w7, v7.y, ay);
  }
  if (j + 4 <= c) {
    int   s0 = __shfl(s_l, j),     s1 = __shfl(s_l, j + 1);
    int   s2 = __shfl(s_l, j + 2), s3 = __shfl(s_l, j + 3);
    float w0 = __shfl(w_l, j),     w1 = __shfl(w_l, j + 1);
    float w2 = __shfl(w_l, j + 2), w3 = __shfl(w_l, j + 3);
    float2 v0 = __bfloat1622float2(h2[(size_t)s0 * 64 + lane]);
    float2 v1 = __bfloat1622float2(h2[(size_t)s1 * 64 + lane]);
    float2 v2 = __bfloat1622float2(h2[(size_t)s2 * 64 + lane]);
    float2 v3 = __bfloat1622float2(h2[(size_t)s3 * 64 + lane]);
    ax = fmaf(w0, v0.x, ax); ay = fmaf(w0, v0.y, ay);
    ax = fmaf(w1, v1.x, ax); ay = fmaf(w1, v1.y, ay);
    ax = fmaf(w2, v2.x, ax); ay = fmaf(w2, v2.y, ay);
    ax = fmaf(w3, v3.x, ax); ay = fmaf(w3, v3.y, ay);
    j += 4;
  }
  for (; j < c; ++j) {
    int   s = __shfl(s_l, j);
    float w = __shfl(w_l, j);
    float2 v = __bfloat1622float2(h2[(size_t)s * 64 + lane]);
    ax = fmaf(w, v.x, ax); ay = fmaf(w, v.y, ay);
  }
  float2 b = ((const float2*)bias)[lane];
  float2 r; r.x = ax + b.x; r.y = ay + b.y;
  ((float2*)out)[(size_t)n * 64 + lane] = r;
}

// ---------------- overflow edges (expected count: 0) ----------------
__global__ __launch_bounds__(128) void ovf_kernel(const __hip_bfloat16* __restrict__ h,
                                                  const int* __restrict__ ovf,
                                                  const int* __restrict__ ovf_cnt,
                                                  const float* __restrict__ dinv,
                                                  float* __restrict__ out) {
  int m = *ovf_cnt; if (m > OVF_CAP) m = OVF_CAP;
  for (int p = blockIdx.x; p < m; p += gridDim.x) {
    int s = ovf[2 * p], d = ovf[2 * p + 1];
    float w = dinv[s] * dinv[d];
    for (int f = threadIdx.x; f < NFEAT; f += blockDim.x)
      atomicAdd(&out[(size_t)d * NFEAT + f],
                w * __bfloat162float(h[(size_t)s * NFEAT + f]));
  }
}

// ---------------- per-graph node counts via binary search (batch sorted) --------
__global__ __launch_bounds__(256) void gcnt_kernel(const int* __restrict__ batch,
                                                   float* __restrict__ invcnt) {
  int g = blockIdx.x * 256 + threadIdx.x;
  if (g >= NGRAPH) return;
  int lo = 0, hi = N_NODES;
  while (lo < hi) { int mid = (lo + hi) >> 1; if (batch[mid] < g) lo = mid + 1; else hi = mid; }
  int lo2 = lo, hi2 = N_NODES;
  while (lo2 < hi2) { int mid = (lo2 + hi2) >> 1; if (batch[mid] < g + 1) lo2 = mid + 1; else hi2 = mid; }
  int c = lo2 - lo;
  invcnt[g] = 1.0f / fmaxf((float)c, 1.0f);
}

// ---------------- pooled sum of relu(h) by (sorted) batch ----------------
#define PCHUNK 64
__global__ __launch_bounds__(64) void pool_kernel(const float* __restrict__ h,
                                                  const int* __restrict__ batch,
                                                  float* __restrict__ gsum) {
  int lane = threadIdx.x;
  int n0 = blockIdx.x * PCHUNK;
  if (n0 >= N_NODES) return;
  int n1 = n0 + PCHUNK; if (n1 > N_NODES) n1 = N_NODES;
  const float2* h2 = (const float2*)h;
  float ax = 0.f, ay = 0.f;
  int cur = batch[n0];
  for (int n = n0; n < n1; ++n) {
    int b = batch[n];                 // wave-uniform
    if (b != cur) {
      atomicAdd(&gsum[cur * NFEAT + 2 * lane], ax);
      atomicAdd(&gsum[cur * NFEAT + 2 * lane + 1], ay);
      ax = 0.f; ay = 0.f; cur = b;
    }
    float2 v = h2[(size_t)n * 64 + lane];
    ax += fmaxf(v.x, 0.f);
    ay += fmaxf(v.y, 0.f);
  }
  atomicAdd(&gsum[cur * NFEAT + 2 * lane], ax);
  atomicAdd(&gsum[cur * NFEAT + 2 * lane + 1], ay);
}

// ---------------- MLP head ----------------
__global__ __launch_bounds__(128) void mlp_kernel(const float* __restrict__ gsum,
                                                  const float* __restrict__ invcnt,
                                                  const float* __restrict__ Wl1,
                                                  const float* __restrict__ bl1,
                                                  const float* __restrict__ Wl2,
                                                  const float* __restrict__ bl2,
                                                  float* __restrict__ out) {
  __shared__ float gr[NFEAT];
  __shared__ float t1[NFEAT];
  int g = blockIdx.x, t = threadIdx.x;
  gr[t] = gsum[g * NFEAT + t] * invcnt[g];
  __syncthreads();
  float acc = bl1[t];
  for (int k = 0; k < NFEAT; ++k) acc = fmaf(gr[k], Wl1[k * NFEAT + t], acc);
  t1[t] = fmaxf(acc, 0.f);
  __syncthreads();
  if (t < NACT) {
    float a2 = bl2[t];
    for (int k = 0; k < NFEAT; ++k) a2 = fmaf(t1[k], Wl2[k * NACT + t], a2);
    out[g * NACT + t] = a2;
  }
}

extern "C" void kernel_launch(void* const* d_in, const int* in_sizes, int n_in,
                              void* d_out, int out_size, void* d_ws, size_t ws_size,
                              hipStream_t stream) {
  const float* x    = (const float*)d_in[0];
  const int*   ei   = (const int*)d_in[1];
  const int*   batch= (const int*)d_in[2];
  const float* W1   = (const float*)d_in[3];
  const float* b1   = (const float*)d_in[4];
  const float* W2   = (const float*)d_in[5];
  const float* b2   = (const float*)d_in[6];
  const float* Wl1  = (const float*)d_in[7];
  const float* bl1  = (const float*)d_in[8];
  const float* Wl2  = (const float*)d_in[9];
  const float* bl2  = (const float*)d_in[10];
  float* out = (float*)d_out;

  const int* srcp = ei;            // edge_index[0]
  const int* dstp = ei + N_EDGES;  // edge_index[1]

  // workspace bump allocator (512B aligned); zeroed region first.
  char* base = (char*)d_ws;
  size_t off = 0;
  auto alloc = [&](size_t bytes) -> void* {
    void* p = base + off;
    off += (bytes + 511) & ~(size_t)511;
    return p;
  };
  int*   cnt     = (int*)alloc((size_t)N_NODES * 4);
  int*   ovfc    = (int*)alloc(4);
  float* gsum    = (float*)alloc((size_t)NGRAPH * NFEAT * 4);
  int*   bucket_cursor = (int*)alloc((size_t)NBUCK * 4);
  size_t zspan   = off;  // everything above must start zeroed
  float* dinv    = (float*)alloc((size_t)N_NODES * 4);
  float* invcnt  = (float*)alloc((size_t)NGRAPH * 4);
  int*   elist   = (int*)alloc((size_t)NBLK2 * BIN_NODES * ECAP * 4); // padded
  int*   ovf     = (int*)alloc((size_t)OVF_CAP * 2 * 4);
  int2*  seg     = (int2*)alloc((size_t)NBUCK * SEGCAP * 8);          // 16 MB
  unsigned short* Wt1 = (unsigned short*)alloc((size_t)NFEAT * NFEAT * 2);
  unsigned short* Wt2 = (unsigned short*)alloc((size_t)NFEAT * NFEAT * 2);
  unsigned short* A = (unsigned short*)alloc((size_t)N_NODES * NFEAT * 2); // bf16 h
  float* B       = (float*)alloc((size_t)N_NODES * NFEAT * 4);             // agg out

  hipMemsetAsync(d_ws, 0, zspan, stream);

  const int NB = (N_NODES + 255) / 256;   // 391
  const int GB = (N_NODES + 63) / 64;     // 1563 gemm blocks

  edgepart_kernel<<<NBLK1, 256, 0, stream>>>(srcp, dstp, bucket_cursor, seg, cnt, ovfc, ovf);
  binbuild_kernel<<<NBLK2, 256, 0, stream>>>(seg, bucket_cursor, cnt, elist, ovfc, ovf);
  dinv_kernel<<<NB, 256, 0, stream>>>(cnt, dinv);
  wt_kernel<<<NFEAT * NFEAT / 256, 256, 0, stream>>>(W1, Wt1);
  wt_kernel<<<NFEAT * NFEAT / 256, 256, 0, stream>>>(W2, Wt2);

  // layer 1: A(bf16) = x @ W1 ; B = agg(A) + selfloop + b1 (relu deferred to gemm2)
  gemm_mfma_kernel<<<GB, 256, 0, stream>>>(x, Wt1, A, 0);
  agg_kernel<<<N_NODES / 4, 256, 0, stream>>>((const __hip_bfloat162*)A, elist, cnt, dinv, b1, B);
  ovf_kernel<<<64, 128, 0, stream>>>((const __hip_bfloat16*)A, ovf, ovfc, dinv, B);

  // layer 2: A(bf16) = relu(B) @ W2 ; B = agg(A) + selfloop + b2 (relu at pool)
  gemm_mfma_kernel<<<GB, 256, 0, stream>>>(B, Wt2, A, 1);
  agg_kernel<<<N_NODES / 4, 256, 0, stream>>>((const __hip_bfloat162*)A, elist, cnt, dinv, b2, B);
  ovf_kernel<<<64, 128, 0, stream>>>((const __hip_bfloat16*)A, ovf, ovfc, dinv, B);

  // pool + head
  gcnt_kernel<<<1, 256, 0, stream>>>(batch, invcnt);
  pool_kernel<<<(N_NODES + PCHUNK - 1) / PCHUNK, 64, 0, stream>>>(B, batch, gsum);
  mlp_kernel<<<NGRAPH, 128, 0, stream>>>(gsum, invcnt, Wl1, bl1, Wl2, bl2, out);
}

// Round 8
// 400.076 us; speedup vs baseline: 1.8810x; 1.0222x over previous
//
#include <hip/hip_runtime.h>
#include <hip/hip_bf16.h>

#define N_NODES 100000
#define N_EDGES 1600000
#define NFEAT   128
#define NGRAPH  256
#define NACT    32
#define ECAP    64
#define OVF_CAP 8192

// ---- two-pass edge partition ----
#define BUCK_SHIFT 9
#define BUCK_NODES 512
#define NBUCK ((N_NODES + BUCK_NODES - 1) / BUCK_NODES)   // 196
#define SEGCAP 10240          // mean 8192, +22 sigma
#define CHUNK 4096            // edges per pass-1 block
#define NBLK1 ((N_EDGES + CHUNK - 1) / CHUNK)             // 391
#define BIN_NODES 128         // pass-2 nodes per block
#define NBLK2 ((N_NODES + BIN_NODES - 1) / BIN_NODES)     // 782

typedef __attribute__((ext_vector_type(8))) short bf16x8;
typedef __attribute__((ext_vector_type(4))) float f32x4;

__device__ inline unsigned short f2bf(float f) {
  __hip_bfloat16 b = __float2bfloat16(f);
  return *reinterpret_cast<unsigned short*>(&b);
}
__device__ inline float2 bfu2f(unsigned u) {
  __hip_bfloat162 t = *reinterpret_cast<__hip_bfloat162*>(&u);
  return __bfloat1622float2(t);
}

// ---------------- dinv from counts (cnt == dst-degree) ----------------
__global__ __launch_bounds__(256) void dinv_kernel(const int* __restrict__ cnt,
                                                   float* __restrict__ dinv) {
  int n = blockIdx.x * 256 + threadIdx.x;
  if (n < N_NODES) dinv[n] = rsqrtf((float)cnt[n] + 1.0f);
}

// ---- pass 1: block-local bucket sort in LDS, dense segment flush ----
// No per-thread edge array (scratch-spill trap, R6); phase C re-reads edges.
__global__ __launch_bounds__(256) void edgepart_kernel(const int* __restrict__ src,
                                                       const int* __restrict__ dst,
                                                       int* __restrict__ bucket_cursor,
                                                       int2* __restrict__ seg,
                                                       int* __restrict__ cnt,
                                                       int* __restrict__ ovf_cnt,
                                                       int* __restrict__ ovf) {
  __shared__ int2 stage[CHUNK];               // 32 KB
  __shared__ int hist[NBUCK], offs[NBUCK], cursor[NBUCK], gbase[NBUCK];
  __shared__ int sc[256];
  int tid = threadIdx.x;
  int e0 = blockIdx.x * CHUNK;
  int m = N_EDGES - e0; if (m > CHUNK) m = CHUNK;

  for (int i = tid; i < NBUCK; i += 256) hist[i] = 0;
  __syncthreads();

  for (int i = tid; i < m; i += 256)
    atomicAdd(&hist[dst[e0 + i] >> BUCK_SHIFT], 1);
  __syncthreads();

  sc[tid] = (tid < NBUCK) ? hist[tid] : 0;
  __syncthreads();
  for (int ofs = 1; ofs < 256; ofs <<= 1) {
    int t = (tid >= ofs) ? sc[tid - ofs] : 0;
    __syncthreads();
    sc[tid] += t;
    __syncthreads();
  }
  if (tid < NBUCK) {
    int o = tid ? sc[tid - 1] : 0;
    offs[tid] = o;
    cursor[tid] = o;
    gbase[tid] = hist[tid] ? atomicAdd(&bucket_cursor[tid], hist[tid]) : 0;
  }
  __syncthreads();

  for (int i = tid; i < m; i += 256) {
    int2 p = make_int2(src[e0 + i], dst[e0 + i]);
    int pos = atomicAdd(&cursor[p.y >> BUCK_SHIFT], 1);
    stage[pos] = p;
  }
  __syncthreads();

  for (int i = tid; i < m; i += 256) {
    int2 p = stage[i];
    int bd = p.y >> BUCK_SHIFT;
    int gpos = gbase[bd] + (i - offs[bd]);
    if (gpos < SEGCAP) {
      seg[(size_t)bd * SEGCAP + gpos] = p;
    } else {                                // ~never: count + defer to ovf fixup
      atomicAdd(&cnt[p.y], 1);
      int o = atomicAdd(ovf_cnt, 1);
      if (o < OVF_CAP) { ovf[2 * o] = p.x; ovf[2 * o + 1] = p.y; }
    }
  }
}

// ---- pass 2: per-128-node elist build in LDS, dense writeback ----
__global__ __launch_bounds__(256) void binbuild_kernel(const int2* __restrict__ seg,
                                                       const int* __restrict__ bucket_cursor,
                                                       int* __restrict__ cnt,
                                                       int* __restrict__ elist,
                                                       int* __restrict__ ovf_cnt,
                                                       int* __restrict__ ovf) {
  __shared__ int lcnt[BIN_NODES];
  __shared__ int lel[BIN_NODES * ECAP];     // 32 KB
  int tid = threadIdx.x;
  int n0 = blockIdx.x * BIN_NODES;
  int pb = n0 >> BUCK_SHIFT;
  if (tid < BIN_NODES) lcnt[tid] = 0;
  __syncthreads();
  int m = bucket_cursor[pb]; if (m > SEGCAP) m = SEGCAP;
  const int2* s = seg + (size_t)pb * SEGCAP;
  for (int e = tid; e < m; e += 256) {
    int2 p = s[e];
    unsigned ln = (unsigned)(p.y - n0);
    if (ln < (unsigned)BIN_NODES) {
      int pos = atomicAdd(&lcnt[ln], 1);
      if (pos < ECAP) {
        lel[(ln << 6) + pos] = p.x;
      } else {
        int o = atomicAdd(ovf_cnt, 1);
        if (o < OVF_CAP) { ovf[2 * o] = p.x; ovf[2 * o + 1] = p.y; }
      }
    }
  }
  __syncthreads();
  if (tid < BIN_NODES) {
    int n = n0 + tid;
    if (n < N_NODES) cnt[n] += lcnt[tid];
  }
  int4* gel = (int4*)(elist + (size_t)n0 * ECAP);
  const int4* lel4 = (const int4*)lel;
  for (int i = tid; i < BIN_NODES * ECAP / 4; i += 256) gel[i] = lel4[i];
}

// ---------------- Wt[n][k] = bf16(W[k][n]) — once per call ----------
__global__ __launch_bounds__(256) void wt_kernel(const float* __restrict__ W,
                                                 unsigned short* __restrict__ Wt) {
  int i = blockIdx.x * 256 + threadIdx.x;
  if (i >= NFEAT * NFEAT) return;
  int n = i >> 7, k = i & 127;
  Wt[n * NFEAT + k] = f2bf(W[k * NFEAT + n]);
}

// ---------------- layer-1 GEMM: C(bf16) = A(f32) @ W via MFMA ------------
__global__ __launch_bounds__(256) void gemm_f32in_kernel(const float* __restrict__ A,
                                                         const unsigned short* __restrict__ Wt,
                                                         unsigned short* __restrict__ C) {
  int tid = threadIdx.x;
  int wave = tid >> 6, lane = tid & 63;
  int q = lane >> 4, r = lane & 15;
  int m0 = blockIdx.x * 64 + wave * 16;
  int arow = m0 + r; if (arow > N_NODES - 1) arow = N_NODES - 1;
  const float* Arow = A + (size_t)arow * NFEAT;

  f32x4 acc[8];
  #pragma unroll
  for (int t = 0; t < 8; ++t) acc[t] = (f32x4){0.f, 0.f, 0.f, 0.f};

  #pragma unroll
  for (int s = 0; s < 4; ++s) {
    int k0 = s * 32 + q * 8;
    float4 a0 = *(const float4*)(Arow + k0);
    float4 a1 = *(const float4*)(Arow + k0 + 4);
    bf16x8 af;
    af[0] = (short)f2bf(a0.x); af[1] = (short)f2bf(a0.y);
    af[2] = (short)f2bf(a0.z); af[3] = (short)f2bf(a0.w);
    af[4] = (short)f2bf(a1.x); af[5] = (short)f2bf(a1.y);
    af[6] = (short)f2bf(a1.z); af[7] = (short)f2bf(a1.w);
    #pragma unroll
    for (int t = 0; t < 8; ++t) {
      bf16x8 bf = *(const bf16x8*)(Wt + (size_t)(t * 16 + r) * NFEAT + k0);
      acc[t] = __builtin_amdgcn_mfma_f32_16x16x32_bf16(af, bf, acc[t], 0, 0, 0);
    }
  }
  #pragma unroll
  for (int t = 0; t < 8; ++t)
    #pragma unroll
    for (int rr = 0; rr < 4; ++rr) {
      int row = m0 + q * 4 + rr;
      if (row < N_NODES)
        C[(size_t)row * NFEAT + t * 16 + r] = f2bf(acc[t][rr]);
    }
}

// ---------------- layer-2 GEMM: C(bf16) = relu(A(bf16)) @ W via MFMA ----------
__global__ __launch_bounds__(256) void gemm_bf16in_kernel(const unsigned short* __restrict__ A,
                                                          const unsigned short* __restrict__ Wt,
                                                          unsigned short* __restrict__ C) {
  int tid = threadIdx.x;
  int wave = tid >> 6, lane = tid & 63;
  int q = lane >> 4, r = lane & 15;
  int m0 = blockIdx.x * 64 + wave * 16;
  int arow = m0 + r; if (arow > N_NODES - 1) arow = N_NODES - 1;
  const unsigned short* Arow = A + (size_t)arow * NFEAT;

  f32x4 acc[8];
  #pragma unroll
  for (int t = 0; t < 8; ++t) acc[t] = (f32x4){0.f, 0.f, 0.f, 0.f};

  #pragma unroll
  for (int s = 0; s < 4; ++s) {
    int k0 = s * 32 + q * 8;
    bf16x8 af = *(const bf16x8*)(Arow + k0);   // direct 16B bf16 load
    #pragma unroll
    for (int i = 0; i < 8; ++i)                // relu: bf16 sign bit == short sign
      af[i] = (short)(af[i] < (short)0 ? (short)0 : af[i]);
    #pragma unroll
    for (int t = 0; t < 8; ++t) {
      bf16x8 bf = *(const bf16x8*)(Wt + (size_t)(t * 16 + r) * NFEAT + k0);
      acc[t] = __builtin_amdgcn_mfma_f32_16x16x32_bf16(af, bf, acc[t], 0, 0, 0);
    }
  }
  #pragma unroll
  for (int t = 0; t < 8; ++t)
    #pragma unroll
    for (int rr = 0; rr < 4; ++rr) {
      int row = m0 + q * 4 + rr;
      if (row < N_NODES)
        C[(size_t)row * NFEAT + t * 16 + r] = f2bf(acc[t][rr]);
    }
}

// ---------------- gather aggregation: one wave per dst node, 16 gathers in flight
// out(bf16)[n] = sum dinv[s]*dinv[n]*h[s] + dinv[n]^2*h[n] + bias
__global__ __launch_bounds__(256) void agg_kernel(const unsigned* __restrict__ hu,
                                                  const int* __restrict__ elist,
                                                  const int* __restrict__ cnt,
                                                  const float* __restrict__ dinv,
                                                  const float* __restrict__ bias,
                                                  unsigned* __restrict__ out) {
  int n = (blockIdx.x * 256 + threadIdx.x) >> 6;
  int lane = threadIdx.x & 63;
  if (n >= N_NODES) return;
  float dn = dinv[n];
  int c = cnt[n]; c = (c > ECAP) ? ECAP : c;
  const int* el = elist + (size_t)n * ECAP;

  int   s_l = (lane < c) ? el[lane] : 0;
  float w_l = (lane < c) ? dinv[s_l] * dn : 0.f;

  float2 hv = bfu2f(hu[(size_t)n * 64 + lane]);
  float sw = dn * dn;
  float ax = sw * hv.x, ay = sw * hv.y;

  int j = 0;
  for (; j + 16 <= c; j += 16) {
    unsigned pv[16]; float w[16];
    #pragma unroll
    for (int u = 0; u < 16; ++u) {
      int s = __shfl(s_l, j + u);
      w[u] = __shfl(w_l, j + u);
      pv[u] = hu[(size_t)s * 64 + lane];     // 16 independent 256B gathers
    }
    #pragma unroll
    for (int u = 0; u < 16; ++u) {
      float2 v = bfu2f(pv[u]);
      ax = fmaf(w[u], v.x, ax); ay = fmaf(w[u], v.y, ay);
    }
  }
  for (; j + 4 <= c; j += 4) {
    unsigned pv[4]; float w[4];
    #pragma unroll
    for (int u = 0; u < 4; ++u) {
      int s = __shfl(s_l, j + u);
      w[u] = __shfl(w_l, j + u);
      pv[u] = hu[(size_t)s * 64 + lane];
    }
    #pragma unroll
    for (int u = 0; u < 4; ++u) {
      float2 v = bfu2f(pv[u]);
      ax = fmaf(w[u], v.x, ax); ay = fmaf(w[u], v.y, ay);
    }
  }
  for (; j < c; ++j) {
    int   s = __shfl(s_l, j);
    float w = __shfl(w_l, j);
    float2 v = bfu2f(hu[(size_t)s * 64 + lane]);
    ax = fmaf(w, v.x, ax); ay = fmaf(w, v.y, ay);
  }
  float2 b = ((const float2*)bias)[lane];
  unsigned r = ((unsigned)f2bf(ay + b.y) << 16) | f2bf(ax + b.x);
  out[(size_t)n * 64 + lane] = r;
}

// ---------------- overflow edges (runs 0 times on this input) ----------------
__device__ void bf16_atomic_add(unsigned short* addr, float val) {
  unsigned* word = (unsigned*)((size_t)addr & ~(size_t)3);
  bool hi = ((size_t)addr & 2) != 0;
  unsigned old = *word, assumed;
  do {
    assumed = old;
    unsigned short cur = hi ? (unsigned short)(assumed >> 16)
                            : (unsigned short)(assumed & 0xFFFF);
    __hip_bfloat16 bb = *reinterpret_cast<__hip_bfloat16*>(&cur);
    unsigned short nb = f2bf(__bfloat162float(bb) + val);
    unsigned newv = hi ? ((assumed & 0x0000FFFFu) | ((unsigned)nb << 16))
                       : ((assumed & 0xFFFF0000u) | nb);
    old = atomicCAS(word, assumed, newv);
  } while (old != assumed);
}

__global__ __launch_bounds__(128) void ovf_kernel(const unsigned short* __restrict__ h,
                                                  const int* __restrict__ ovf,
                                                  const int* __restrict__ ovf_cnt,
                                                  const float* __restrict__ dinv,
                                                  unsigned short* __restrict__ out) {
  int m = *ovf_cnt; if (m > OVF_CAP) m = OVF_CAP;
  for (int p = blockIdx.x; p < m; p += gridDim.x) {
    int s = ovf[2 * p], d = ovf[2 * p + 1];
    float w = dinv[s] * dinv[d];
    for (int f = threadIdx.x; f < NFEAT; f += blockDim.x) {
      unsigned short hs = h[(size_t)s * NFEAT + f];
      __hip_bfloat16 hb = *reinterpret_cast<__hip_bfloat16*>(&hs);
      bf16_atomic_add(&out[(size_t)d * NFEAT + f], w * __bfloat162float(hb));
    }
  }
}

// ---------------- per-graph node counts via binary search (batch sorted) --------
__global__ __launch_bounds__(256) void gcnt_kernel(const int* __restrict__ batch,
                                                   float* __restrict__ invcnt) {
  int g = blockIdx.x * 256 + threadIdx.x;
  if (g >= NGRAPH) return;
  int lo = 0, hi = N_NODES;
  while (lo < hi) { int mid = (lo + hi) >> 1; if (batch[mid] < g) lo = mid + 1; else hi = mid; }
  int lo2 = lo, hi2 = N_NODES;
  while (lo2 < hi2) { int mid = (lo2 + hi2) >> 1; if (batch[mid] < g + 1) lo2 = mid + 1; else hi2 = mid; }
  int c = lo2 - lo;
  invcnt[g] = 1.0f / fmaxf((float)c, 1.0f);
}

// ---------------- pooled sum of relu(h) by (sorted) batch, h bf16 --------------
#define PCHUNK 64
__global__ __launch_bounds__(64) void pool_kernel(const unsigned* __restrict__ hu,
                                                  const int* __restrict__ batch,
                                                  float* __restrict__ gsum) {
  int lane = threadIdx.x;
  int n0 = blockIdx.x * PCHUNK;
  if (n0 >= N_NODES) return;
  int n1 = n0 + PCHUNK; if (n1 > N_NODES) n1 = N_NODES;
  float ax = 0.f, ay = 0.f;
  int cur = batch[n0];
  for (int n = n0; n < n1; ++n) {
    int b = batch[n];
    if (b != cur) {
      atomicAdd(&gsum[cur * NFEAT + 2 * lane], ax);
      atomicAdd(&gsum[cur * NFEAT + 2 * lane + 1], ay);
      ax = 0.f; ay = 0.f; cur = b;
    }
    float2 v = bfu2f(hu[(size_t)n * 64 + lane]);
    ax += fmaxf(v.x, 0.f);
    ay += fmaxf(v.y, 0.f);
  }
  atomicAdd(&gsum[cur * NFEAT + 2 * lane], ax);
  atomicAdd(&gsum[cur * NFEAT + 2 * lane + 1], ay);
}

// ---------------- MLP head ----------------
__global__ __launch_bounds__(128) void mlp_kernel(const float* __restrict__ gsum,
                                                  const float* __restrict__ invcnt,
                                                  const float* __restrict__ Wl1,
                                                  const float* __restrict__ bl1,
                                                  const float* __restrict__ Wl2,
                                                  const float* __restrict__ bl2,
                                                  float* __restrict__ out) {
  __shared__ float gr[NFEAT];
  __shared__ float t1[NFEAT];
  int g = blockIdx.x, t = threadIdx.x;
  gr[t] = gsum[g * NFEAT + t] * invcnt[g];
  __syncthreads();
  float acc = bl1[t];
  for (int k = 0; k < NFEAT; ++k) acc = fmaf(gr[k], Wl1[k * NFEAT + t], acc);
  t1[t] = fmaxf(acc, 0.f);
  __syncthreads();
  if (t < NACT) {
    float a2 = bl2[t];
    for (int k = 0; k < NFEAT; ++k) a2 = fmaf(t1[k], Wl2[k * NACT + t], a2);
    out[g * NACT + t] = a2;
  }
}

extern "C" void kernel_launch(void* const* d_in, const int* in_sizes, int n_in,
                              void* d_out, int out_size, void* d_ws, size_t ws_size,
                              hipStream_t stream) {
  const float* x    = (const float*)d_in[0];
  const int*   ei   = (const int*)d_in[1];
  const int*   batch= (const int*)d_in[2];
  const float* W1   = (const float*)d_in[3];
  const float* b1   = (const float*)d_in[4];
  const float* W2   = (const float*)d_in[5];
  const float* b2   = (const float*)d_in[6];
  const float* Wl1  = (const float*)d_in[7];
  const float* bl1  = (const float*)d_in[8];
  const float* Wl2  = (const float*)d_in[9];
  const float* bl2  = (const float*)d_in[10];
  float* out = (float*)d_out;

  const int* srcp = ei;            // edge_index[0]
  const int* dstp = ei + N_EDGES;  // edge_index[1]

  char* base = (char*)d_ws;
  size_t off = 0;
  auto alloc = [&](size_t bytes) -> void* {
    void* p = base + off;
    off += (bytes + 511) & ~(size_t)511;
    return p;
  };
  int*   cnt     = (int*)alloc((size_t)N_NODES * 4);
  int*   ovfc    = (int*)alloc(4);
  float* gsum    = (float*)alloc((size_t)NGRAPH * NFEAT * 4);
  int*   bucket_cursor = (int*)alloc((size_t)NBUCK * 4);
  size_t zspan   = off;  // everything above must start zeroed
  float* dinv    = (float*)alloc((size_t)N_NODES * 4);
  float* invcnt  = (float*)alloc((size_t)NGRAPH * 4);
  int*   elist   = (int*)alloc((size_t)NBLK2 * BIN_NODES * ECAP * 4); // padded
  int*   ovf     = (int*)alloc((size_t)OVF_CAP * 2 * 4);
  int2*  seg     = (int2*)alloc((size_t)NBUCK * SEGCAP * 8);          // 16 MB
  unsigned short* Wt1 = (unsigned short*)alloc((size_t)NFEAT * NFEAT * 2);
  unsigned short* Wt2 = (unsigned short*)alloc((size_t)NFEAT * NFEAT * 2);
  unsigned short* A = (unsigned short*)alloc((size_t)N_NODES * NFEAT * 2); // bf16
  unsigned short* B = (unsigned short*)alloc((size_t)N_NODES * NFEAT * 2); // bf16

  hipMemsetAsync(d_ws, 0, zspan, stream);

  const int NB = (N_NODES + 255) / 256;   // 391
  const int GB = (N_NODES + 63) / 64;     // 1563 gemm blocks

  edgepart_kernel<<<NBLK1, 256, 0, stream>>>(srcp, dstp, bucket_cursor, seg, cnt, ovfc, ovf);
  binbuild_kernel<<<NBLK2, 256, 0, stream>>>(seg, bucket_cursor, cnt, elist, ovfc, ovf);
  dinv_kernel<<<NB, 256, 0, stream>>>(cnt, dinv);
  wt_kernel<<<NFEAT * NFEAT / 256, 256, 0, stream>>>(W1, Wt1);
  wt_kernel<<<NFEAT * NFEAT / 256, 256, 0, stream>>>(W2, Wt2);

  // layer 1: A = x @ W1 ; B = agg(A) + selfloop + b1 (relu deferred to gemm2)
  gemm_f32in_kernel<<<GB, 256, 0, stream>>>(x, Wt1, A);
  agg_kernel<<<N_NODES / 4, 256, 0, stream>>>((const unsigned*)A, elist, cnt, dinv, b1, (unsigned*)B);
  ovf_kernel<<<64, 128, 0, stream>>>(A, ovf, ovfc, dinv, B);

  // layer 2: A = relu(B) @ W2 ; B = agg(A) + selfloop + b2 (relu at pool)
  gemm_bf16in_kernel<<<GB, 256, 0, stream>>>(B, Wt2, A);
  agg_kernel<<<N_NODES / 4, 256, 0, stream>>>((const unsigned*)A, elist, cnt, dinv, b2, (unsigned*)B);
  ovf_kernel<<<64, 128, 0, stream>>>(A, ovf, ovfc, dinv, B);

  // pool + head
  gcnt_kernel<<<1, 256, 0, stream>>>(batch, invcnt);
  pool_kernel<<<(N_NODES + PCHUNK - 1) / PCHUNK, 64, 0, stream>>>((const unsigned*)B, batch, gsum);
  mlp_kernel<<<NGRAPH, 128, 0, stream>>>(gsum, invcnt, Wl1, bl1, Wl2, bl2, out);
}

// Round 9
// 374.013 us; speedup vs baseline: 2.0121x; 1.0697x over previous
//
#include <hip/hip_runtime.h>
#include <hip/hip_bf16.h>

#define N_NODES 100000
#define N_EDGES 1600000
#define NFEAT   128
#define NGRAPH  256
#define NACT    32
#define ECAP    64
#define OVF_CAP 8192

// ---- two-pass edge partition ----
#define BUCK_SHIFT 9
#define BUCK_NODES 512
#define NBUCK ((N_NODES + BUCK_NODES - 1) / BUCK_NODES)   // 196
#define SEGCAP 10240          // mean 8192, +22 sigma
#define CHUNK 4096            // edges per pass-1 block
#define NBLK1 ((N_EDGES + CHUNK - 1) / CHUNK)             // 391
#define BIN_NODES 128         // pass-2 nodes per block
#define NBLK2 ((N_NODES + BIN_NODES - 1) / BIN_NODES)     // 782

typedef __attribute__((ext_vector_type(8))) short bf16x8;
typedef __attribute__((ext_vector_type(4))) float f32x4;

__device__ inline unsigned short f2bf(float f) {
  __hip_bfloat16 b = __float2bfloat16(f);
  return *reinterpret_cast<unsigned short*>(&b);
}
__device__ inline float2 bfu2f(unsigned u) {
  __hip_bfloat162 t = *reinterpret_cast<__hip_bfloat162*>(&u);
  return __bfloat1622float2(t);
}

// ---- pass 1: block-local bucket sort in LDS, dense segment flush ----
// No per-thread edge array (scratch-spill trap, R6); phase C re-reads edges.
__global__ __launch_bounds__(256) void edgepart_kernel(const int* __restrict__ src,
                                                       const int* __restrict__ dst,
                                                       int* __restrict__ bucket_cursor,
                                                       int2* __restrict__ seg,
                                                       int* __restrict__ cnt,
                                                       int* __restrict__ ovf_cnt,
                                                       int* __restrict__ ovf) {
  __shared__ int2 stage[CHUNK];               // 32 KB
  __shared__ int hist[NBUCK], offs[NBUCK], cursor[NBUCK], gbase[NBUCK];
  __shared__ int sc[256];
  int tid = threadIdx.x;
  int e0 = blockIdx.x * CHUNK;
  int m = N_EDGES - e0; if (m > CHUNK) m = CHUNK;

  for (int i = tid; i < NBUCK; i += 256) hist[i] = 0;
  __syncthreads();

  for (int i = tid; i < m; i += 256)
    atomicAdd(&hist[dst[e0 + i] >> BUCK_SHIFT], 1);
  __syncthreads();

  sc[tid] = (tid < NBUCK) ? hist[tid] : 0;
  __syncthreads();
  for (int ofs = 1; ofs < 256; ofs <<= 1) {
    int t = (tid >= ofs) ? sc[tid - ofs] : 0;
    __syncthreads();
    sc[tid] += t;
    __syncthreads();
  }
  if (tid < NBUCK) {
    int o = tid ? sc[tid - 1] : 0;
    offs[tid] = o;
    cursor[tid] = o;
    gbase[tid] = hist[tid] ? atomicAdd(&bucket_cursor[tid], hist[tid]) : 0;
  }
  __syncthreads();

  for (int i = tid; i < m; i += 256) {
    int2 p = make_int2(src[e0 + i], dst[e0 + i]);
    int pos = atomicAdd(&cursor[p.y >> BUCK_SHIFT], 1);
    stage[pos] = p;
  }
  __syncthreads();

  for (int i = tid; i < m; i += 256) {
    int2 p = stage[i];
    int bd = p.y >> BUCK_SHIFT;
    int gpos = gbase[bd] + (i - offs[bd]);
    if (gpos < SEGCAP) {
      seg[(size_t)bd * SEGCAP + gpos] = p;
    } else {                                // ~never: count + defer to ovf fixup
      atomicAdd(&cnt[p.y], 1);
      int o = atomicAdd(ovf_cnt, 1);
      if (o < OVF_CAP) { ovf[2 * o] = p.x; ovf[2 * o + 1] = p.y; }
    }
  }
}

// ---- pass 2: per-128-node elist build in LDS, dense writeback (+dinv fused) ----
__global__ __launch_bounds__(256) void binbuild_kernel(const int2* __restrict__ seg,
                                                       const int* __restrict__ bucket_cursor,
                                                       int* __restrict__ cnt,
                                                       float* __restrict__ dinv,
                                                       int* __restrict__ elist,
                                                       int* __restrict__ ovf_cnt,
                                                       int* __restrict__ ovf) {
  __shared__ int lcnt[BIN_NODES];
  __shared__ int lel[BIN_NODES * ECAP];     // 32 KB
  int tid = threadIdx.x;
  int n0 = blockIdx.x * BIN_NODES;
  int pb = n0 >> BUCK_SHIFT;
  if (tid < BIN_NODES) lcnt[tid] = 0;
  __syncthreads();
  int m = bucket_cursor[pb]; if (m > SEGCAP) m = SEGCAP;
  const int2* s = seg + (size_t)pb * SEGCAP;
  for (int e = tid; e < m; e += 256) {
    int2 p = s[e];
    unsigned ln = (unsigned)(p.y - n0);
    if (ln < (unsigned)BIN_NODES) {
      int pos = atomicAdd(&lcnt[ln], 1);
      if (pos < ECAP) {
        lel[(ln << 6) + pos] = p.x;
      } else {
        int o = atomicAdd(ovf_cnt, 1);
        if (o < OVF_CAP) { ovf[2 * o] = p.x; ovf[2 * o + 1] = p.y; }
      }
    }
  }
  __syncthreads();
  if (tid < BIN_NODES) {
    int n = n0 + tid;
    if (n < N_NODES) {
      int tot = cnt[n] + lcnt[tid];          // cnt[n]: pass-1 ovf-capped edges only
      cnt[n] = tot;                          // safe: block owns node range
      dinv[n] = rsqrtf((float)tot + 1.0f);   // fused dinv
    }
  }
  int4* gel = (int4*)(elist + (size_t)n0 * ECAP);
  const int4* lel4 = (const int4*)lel;
  for (int i = tid; i < BIN_NODES * ECAP / 4; i += 256) gel[i] = lel4[i];
}

// ---------------- Wt[n][k] = bf16(W[k][n]) for both layers, one launch --------
__global__ __launch_bounds__(256) void wt2_kernel(const float* __restrict__ W1,
                                                  const float* __restrict__ W2,
                                                  unsigned short* __restrict__ Wt1,
                                                  unsigned short* __restrict__ Wt2) {
  int i = blockIdx.x * 256 + threadIdx.x;
  int which = i >> 14;                 // 16384 elems per matrix
  int idx = i & 16383;
  int n = idx >> 7, k = idx & 127;
  if (which == 0) Wt1[n * NFEAT + k] = f2bf(W1[k * NFEAT + n]);
  else            Wt2[n * NFEAT + k] = f2bf(W2[k * NFEAT + n]);
}

// ---------------- layer-1 GEMM: C(bf16) = A(f32) @ W via MFMA ------------
__global__ __launch_bounds__(256) void gemm_f32in_kernel(const float* __restrict__ A,
                                                         const unsigned short* __restrict__ Wt,
                                                         unsigned short* __restrict__ C) {
  int tid = threadIdx.x;
  int wave = tid >> 6, lane = tid & 63;
  int q = lane >> 4, r = lane & 15;
  int m0 = blockIdx.x * 64 + wave * 16;
  int arow = m0 + r; if (arow > N_NODES - 1) arow = N_NODES - 1;
  const float* Arow = A + (size_t)arow * NFEAT;

  f32x4 acc[8];
  #pragma unroll
  for (int t = 0; t < 8; ++t) acc[t] = (f32x4){0.f, 0.f, 0.f, 0.f};

  #pragma unroll
  for (int s = 0; s < 4; ++s) {
    int k0 = s * 32 + q * 8;
    float4 a0 = *(const float4*)(Arow + k0);
    float4 a1 = *(const float4*)(Arow + k0 + 4);
    bf16x8 af;
    af[0] = (short)f2bf(a0.x); af[1] = (short)f2bf(a0.y);
    af[2] = (short)f2bf(a0.z); af[3] = (short)f2bf(a0.w);
    af[4] = (short)f2bf(a1.x); af[5] = (short)f2bf(a1.y);
    af[6] = (short)f2bf(a1.z); af[7] = (short)f2bf(a1.w);
    #pragma unroll
    for (int t = 0; t < 8; ++t) {
      bf16x8 bf = *(const bf16x8*)(Wt + (size_t)(t * 16 + r) * NFEAT + k0);
      acc[t] = __builtin_amdgcn_mfma_f32_16x16x32_bf16(af, bf, acc[t], 0, 0, 0);
    }
  }
  #pragma unroll
  for (int t = 0; t < 8; ++t)
    #pragma unroll
    for (int rr = 0; rr < 4; ++rr) {
      int row = m0 + q * 4 + rr;
      if (row < N_NODES)
        C[(size_t)row * NFEAT + t * 16 + r] = f2bf(acc[t][rr]);
    }
}

// ---------------- layer-2 GEMM: C(bf16) = relu(A(bf16)) @ W via MFMA ----------
__global__ __launch_bounds__(256) void gemm_bf16in_kernel(const unsigned short* __restrict__ A,
                                                          const unsigned short* __restrict__ Wt,
                                                          unsigned short* __restrict__ C) {
  int tid = threadIdx.x;
  int wave = tid >> 6, lane = tid & 63;
  int q = lane >> 4, r = lane & 15;
  int m0 = blockIdx.x * 64 + wave * 16;
  int arow = m0 + r; if (arow > N_NODES - 1) arow = N_NODES - 1;
  const unsigned short* Arow = A + (size_t)arow * NFEAT;

  f32x4 acc[8];
  #pragma unroll
  for (int t = 0; t < 8; ++t) acc[t] = (f32x4){0.f, 0.f, 0.f, 0.f};

  #pragma unroll
  for (int s = 0; s < 4; ++s) {
    int k0 = s * 32 + q * 8;
    bf16x8 af = *(const bf16x8*)(Arow + k0);   // direct 16B bf16 load
    #pragma unroll
    for (int i = 0; i < 8; ++i)                // relu: bf16 sign bit == short sign
      af[i] = (short)(af[i] < (short)0 ? (short)0 : af[i]);
    #pragma unroll
    for (int t = 0; t < 8; ++t) {
      bf16x8 bf = *(const bf16x8*)(Wt + (size_t)(t * 16 + r) * NFEAT + k0);
      acc[t] = __builtin_amdgcn_mfma_f32_16x16x32_bf16(af, bf, acc[t], 0, 0, 0);
    }
  }
  #pragma unroll
  for (int t = 0; t < 8; ++t)
    #pragma unroll
    for (int rr = 0; rr < 4; ++rr) {
      int row = m0 + q * 4 + rr;
      if (row < N_NODES)
        C[(size_t)row * NFEAT + t * 16 + r] = f2bf(acc[t][rr]);
    }
}

// ---------------- gather aggregation: HALF-WAVE per node ----------------
// 2 nodes/wave, 32 lanes/node, uint2 (4 feats) per lane: one load instr serves
// 2 edges. Slots >= c padded with (s=n, w=0): self-row load, zero contribution.
__global__ __launch_bounds__(256) void agg_kernel(const uint2* __restrict__ h2,
                                                  const int* __restrict__ elist,
                                                  const int* __restrict__ cnt,
                                                  const float* __restrict__ dinv,
                                                  const float* __restrict__ bias,
                                                  uint2* __restrict__ out) {
  int wid = (blockIdx.x * 256 + threadIdx.x) >> 6;
  int lane = threadIdx.x & 63;
  int hl = lane & 31;
  int n = wid * 2 + (lane >> 5);
  if (n >= N_NODES) return;
  float dn = dinv[n];
  int c = cnt[n]; c = (c > ECAP) ? ECAP : c;
  const int* el = elist + (size_t)n * ECAP;

  // lane-parallel prefetch of slots: 0..31 in (s0,w0), 32..63 in (s1,w1)
  int   s0 = (hl < c)      ? el[hl]      : n;
  float w0 = (hl < c)      ? dinv[s0] * dn : 0.f;
  int   s1 = (hl + 32 < c) ? el[hl + 32] : n;
  float w1 = (hl + 32 < c) ? dinv[s1] * dn : 0.f;

  int cA = __shfl(c, 0), cB = __shfl(c, 32);
  int cmax = cA > cB ? cA : cB;

  uint2 hv = h2[(size_t)n * 32 + hl];
  float2 vlo = bfu2f(hv.x), vhi = bfu2f(hv.y);
  float sw = dn * dn;
  float a0 = sw * vlo.x, a1 = sw * vlo.y, a2 = sw * vhi.x, a3 = sw * vhi.y;

  // phase 1: slots [0, min(cmax,32))
  int e1 = cmax < 32 ? cmax : 32;
  int j = 0;
  for (; j + 8 <= e1; j += 8) {
    uint2 pv[8]; float w[8];
    #pragma unroll
    for (int u = 0; u < 8; ++u) {
      int s = __shfl(s0, j + u, 32);          // per-half broadcast
      w[u] = __shfl(w0, j + u, 32);
      pv[u] = h2[(size_t)s * 32 + hl];        // 8 independent 512B/wave gathers
    }
    #pragma unroll
    for (int u = 0; u < 8; ++u) {
      float2 lo = bfu2f(pv[u].x), hi = bfu2f(pv[u].y);
      a0 = fmaf(w[u], lo.x, a0); a1 = fmaf(w[u], lo.y, a1);
      a2 = fmaf(w[u], hi.x, a2); a3 = fmaf(w[u], hi.y, a3);
    }
  }
  for (; j < e1; ++j) {
    int s = __shfl(s0, j, 32);
    float w = __shfl(w0, j, 32);
    uint2 pv = h2[(size_t)s * 32 + hl];
    float2 lo = bfu2f(pv.x), hi = bfu2f(pv.y);
    a0 = fmaf(w, lo.x, a0); a1 = fmaf(w, lo.y, a1);
    a2 = fmaf(w, hi.x, a2); a3 = fmaf(w, hi.y, a3);
  }
  // phase 2: slots [32, cmax)
  if (cmax > 32) {
    j = 32;
    for (; j + 8 <= cmax; j += 8) {
      uint2 pv[8]; float w[8];
      #pragma unroll
      for (int u = 0; u < 8; ++u) {
        int s = __shfl(s1, j - 32 + u, 32);
        w[u] = __shfl(w1, j - 32 + u, 32);
        pv[u] = h2[(size_t)s * 32 + hl];
      }
      #pragma unroll
      for (int u = 0; u < 8; ++u) {
        float2 lo = bfu2f(pv[u].x), hi = bfu2f(pv[u].y);
        a0 = fmaf(w[u], lo.x, a0); a1 = fmaf(w[u], lo.y, a1);
        a2 = fmaf(w[u], hi.x, a2); a3 = fmaf(w[u], hi.y, a3);
      }
    }
    for (; j < cmax; ++j) {
      int s = __shfl(s1, j - 32, 32);
      float w = __shfl(w1, j - 32, 32);
      uint2 pv = h2[(size_t)s * 32 + hl];
      float2 lo = bfu2f(pv.x), hi = bfu2f(pv.y);
      a0 = fmaf(w, lo.x, a0); a1 = fmaf(w, lo.y, a1);
      a2 = fmaf(w, hi.x, a2); a3 = fmaf(w, hi.y, a3);
    }
  }
  float4 b4 = ((const float4*)bias)[hl];
  uint2 r;
  r.x = ((unsigned)f2bf(a1 + b4.y) << 16) | f2bf(a0 + b4.x);
  r.y = ((unsigned)f2bf(a3 + b4.w) << 16) | f2bf(a2 + b4.z);
  out[(size_t)n * 32 + hl] = r;
}

// ---------------- overflow edges (runs 0 times on this input) ----------------
__device__ void bf16_atomic_add(unsigned short* addr, float val) {
  unsigned* word = (unsigned*)((size_t)addr & ~(size_t)3);
  bool hi = ((size_t)addr & 2) != 0;
  unsigned old = *word, assumed;
  do {
    assumed = old;
    unsigned short cur = hi ? (unsigned short)(assumed >> 16)
                            : (unsigned short)(assumed & 0xFFFF);
    __hip_bfloat16 bb = *reinterpret_cast<__hip_bfloat16*>(&cur);
    unsigned short nb = f2bf(__bfloat162float(bb) + val);
    unsigned newv = hi ? ((assumed & 0x0000FFFFu) | ((unsigned)nb << 16))
                       : ((assumed & 0xFFFF0000u) | nb);
    old = atomicCAS(word, assumed, newv);
  } while (old != assumed);
}

__global__ __launch_bounds__(128) void ovf_kernel(const unsigned short* __restrict__ h,
                                                  const int* __restrict__ ovf,
                                                  const int* __restrict__ ovf_cnt,
                                                  const float* __restrict__ dinv,
                                                  unsigned short* __restrict__ out) {
  int m = *ovf_cnt; if (m > OVF_CAP) m = OVF_CAP;
  for (int p = blockIdx.x; p < m; p += gridDim.x) {
    int s = ovf[2 * p], d = ovf[2 * p + 1];
    float w = dinv[s] * dinv[d];
    for (int f = threadIdx.x; f < NFEAT; f += blockDim.x) {
      unsigned short hs = h[(size_t)s * NFEAT + f];
      __hip_bfloat16 hb = *reinterpret_cast<__hip_bfloat16*>(&hs);
      bf16_atomic_add(&out[(size_t)d * NFEAT + f], w * __bfloat162float(hb));
    }
  }
}

// ---------------- pooled sum of relu(h) by (sorted) batch, h bf16 --------------
#define PCHUNK 64
__global__ __launch_bounds__(64) void pool_kernel(const unsigned* __restrict__ hu,
                                                  const int* __restrict__ batch,
                                                  float* __restrict__ gsum) {
  int lane = threadIdx.x;
  int n0 = blockIdx.x * PCHUNK;
  if (n0 >= N_NODES) return;
  int n1 = n0 + PCHUNK; if (n1 > N_NODES) n1 = N_NODES;
  float ax = 0.f, ay = 0.f;
  int cur = batch[n0];
  for (int n = n0; n < n1; ++n) {
    int b = batch[n];
    if (b != cur) {
      atomicAdd(&gsum[cur * NFEAT + 2 * lane], ax);
      atomicAdd(&gsum[cur * NFEAT + 2 * lane + 1], ay);
      ax = 0.f; ay = 0.f; cur = b;
    }
    float2 v = bfu2f(hu[(size_t)n * 64 + lane]);
    ax += fmaxf(v.x, 0.f);
    ay += fmaxf(v.y, 0.f);
  }
  atomicAdd(&gsum[cur * NFEAT + 2 * lane], ax);
  atomicAdd(&gsum[cur * NFEAT + 2 * lane + 1], ay);
}

// ---------------- MLP head (graph-count binary search fused in) ----------------
__global__ __launch_bounds__(128) void mlp_kernel(const float* __restrict__ gsum,
                                                  const int* __restrict__ batch,
                                                  const float* __restrict__ Wl1,
                                                  const float* __restrict__ bl1,
                                                  const float* __restrict__ Wl2,
                                                  const float* __restrict__ bl2,
                                                  float* __restrict__ out) {
  __shared__ float gr[NFEAT];
  __shared__ float t1[NFEAT];
  __shared__ float sinv;
  int g = blockIdx.x, t = threadIdx.x;
  if (t == 0) {
    int lo = 0, hi = N_NODES;
    while (lo < hi) { int mid = (lo + hi) >> 1; if (batch[mid] < g) lo = mid + 1; else hi = mid; }
    int lo2 = lo, hi2 = N_NODES;
    while (lo2 < hi2) { int mid = (lo2 + hi2) >> 1; if (batch[mid] < g + 1) lo2 = mid + 1; else hi2 = mid; }
    sinv = 1.0f / fmaxf((float)(lo2 - lo), 1.0f);
  }
  __syncthreads();
  gr[t] = gsum[g * NFEAT + t] * sinv;
  __syncthreads();
  float acc = bl1[t];
  for (int k = 0; k < NFEAT; ++k) acc = fmaf(gr[k], Wl1[k * NFEAT + t], acc);
  t1[t] = fmaxf(acc, 0.f);
  __syncthreads();
  if (t < NACT) {
    float a2 = bl2[t];
    for (int k = 0; k < NFEAT; ++k) a2 = fmaf(t1[k], Wl2[k * NACT + t], a2);
    out[g * NACT + t] = a2;
  }
}

extern "C" void kernel_launch(void* const* d_in, const int* in_sizes, int n_in,
                              void* d_out, int out_size, void* d_ws, size_t ws_size,
                              hipStream_t stream) {
  const float* x    = (const float*)d_in[0];
  const int*   ei   = (const int*)d_in[1];
  const int*   batch= (const int*)d_in[2];
  const float* W1   = (const float*)d_in[3];
  const float* b1   = (const float*)d_in[4];
  const float* W2   = (const float*)d_in[5];
  const float* b2   = (const float*)d_in[6];
  const float* Wl1  = (const float*)d_in[7];
  const float* bl1  = (const float*)d_in[8];
  const float* Wl2  = (const float*)d_in[9];
  const float* bl2  = (const float*)d_in[10];
  float* out = (float*)d_out;

  const int* srcp = ei;            // edge_index[0]
  const int* dstp = ei + N_EDGES;  // edge_index[1]

  char* base = (char*)d_ws;
  size_t off = 0;
  auto alloc = [&](size_t bytes) -> void* {
    void* p = base + off;
    off += (bytes + 511) & ~(size_t)511;
    return p;
  };
  int*   cnt     = (int*)alloc((size_t)N_NODES * 4);
  int*   ovfc    = (int*)alloc(4);
  float* gsum    = (float*)alloc((size_t)NGRAPH * NFEAT * 4);
  int*   bucket_cursor = (int*)alloc((size_t)NBUCK * 4);
  size_t zspan   = off;  // everything above must start zeroed
  float* dinv    = (float*)alloc((size_t)N_NODES * 4);
  int*   elist   = (int*)alloc((size_t)NBLK2 * BIN_NODES * ECAP * 4); // padded
  int*   ovf     = (int*)alloc((size_t)OVF_CAP * 2 * 4);
  int2*  seg     = (int2*)alloc((size_t)NBUCK * SEGCAP * 8);          // 16 MB
  unsigned short* Wt1 = (unsigned short*)alloc((size_t)NFEAT * NFEAT * 2);
  unsigned short* Wt2 = (unsigned short*)alloc((size_t)NFEAT * NFEAT * 2);
  unsigned short* A = (unsigned short*)alloc((size_t)N_NODES * NFEAT * 2); // bf16
  unsigned short* B = (unsigned short*)alloc((size_t)N_NODES * NFEAT * 2); // bf16

  hipMemsetAsync(d_ws, 0, zspan, stream);

  const int GB = (N_NODES + 63) / 64;     // 1563 gemm blocks
  const int AB = (N_NODES + 7) / 8;       // 12500 agg blocks (8 nodes/block)

  edgepart_kernel<<<NBLK1, 256, 0, stream>>>(srcp, dstp, bucket_cursor, seg, cnt, ovfc, ovf);
  binbuild_kernel<<<NBLK2, 256, 0, stream>>>(seg, bucket_cursor, cnt, dinv, elist, ovfc, ovf);
  wt2_kernel<<<2 * NFEAT * NFEAT / 256, 256, 0, stream>>>(W1, W2, Wt1, Wt2);

  // layer 1: A = x @ W1 ; B = agg(A) + selfloop + b1 (relu deferred to gemm2)
  gemm_f32in_kernel<<<GB, 256, 0, stream>>>(x, Wt1, A);
  agg_kernel<<<AB, 256, 0, stream>>>((const uint2*)A, elist, cnt, dinv, b1, (uint2*)B);
  ovf_kernel<<<64, 128, 0, stream>>>(A, ovf, ovfc, dinv, B);

  // layer 2: A = relu(B) @ W2 ; B = agg(A) + selfloop + b2 (relu at pool)
  gemm_bf16in_kernel<<<GB, 256, 0, stream>>>(B, Wt2, A);
  agg_kernel<<<AB, 256, 0, stream>>>((const uint2*)A, elist, cnt, dinv, b2, (uint2*)B);
  ovf_kernel<<<64, 128, 0, stream>>>(A, ovf, ovfc, dinv, B);

  // pool + head
  pool_kernel<<<(N_NODES + PCHUNK - 1) / PCHUNK, 64, 0, stream>>>((const unsigned*)B, batch, gsum);
  mlp_kernel<<<NGRAPH, 128, 0, stream>>>(gsum, batch, Wl1, bl1, Wl2, bl2, out);
}